// Round 1
// baseline (2052.397 us; speedup 1.0000x reference)
//
#include <hip/hip_runtime.h>
#include <hip/hip_bf16.h>
#include <math.h>

// ---------------------------------------------------------------------------
// VQVAE forward, fp32 baseline.
// Outputs (flat, concatenated): x_tilde[16384,768], z_e_x[16384,500],
// z_q_x[16384,500], logits[16384,43], kl_div[1]
// ---------------------------------------------------------------------------

#define B_ROWS 16384
#define TILE 64
#define BK 16

constexpr size_t X_TILDE_OFF = 0;                      // 16384*768 = 12,582,912
constexpr size_t ZE_OFF      = 12582912;               // 16384*500 =  8,192,000
constexpr size_t ZQ_OFF      = 20774912;               // 16384*500 =  8,192,000
constexpr size_t LOG_OFF     = 28966912;               // 16384*43  =    704,512
constexpr size_t KL_OFF      = 29671424;               // 1

// ws layout in floats. Z aliases h: h's last read (mu_logvar gemm) happens
// before any Z write (head_kernel / vae_sample).
constexpr size_t WS_Z   = 0;                           // [16384][1088]  (71.3 MB)
constexpr size_t WS_H   = 0;                           // [16384][1024]  (64 MB, aliased)
constexpr size_t WS_ML  = 17825792;                    // [16384][2048]  (128 MB)
constexpr size_t WS_WDP = WS_ML + 33554432;            // [768][1088]    (3.3 MB)

// ---------------------------------------------------------------------------
// C[M x N] = act(A[M x K] @ B[N x K]^T + bias).  A,B row-major, K contiguous.
// 64x64 tile, 256 threads, 4x4 microtile, BK=16, LDS padded +4 (2-way max).
// NGUARD: predicate B-row loads and C stores on n < N (also enables K-tail).
// ---------------------------------------------------------------------------
template<bool RELU, bool NGUARD>
__global__ __launch_bounds__(256) void gemm_tn(
    const float* __restrict__ A, int lda,
    const float* __restrict__ Bw, int ldb,
    const float* __restrict__ bias,
    float* __restrict__ C, int ldc, int N, int K)
{
    __shared__ float As[BK][TILE + 4];
    __shared__ float Bs[BK][TILE + 4];
    const int t    = threadIdx.x;
    const int bn   = blockIdx.x, bm = blockIdx.y;
    const int row0 = bm * TILE, col0 = bn * TILE;
    const int sr   = t >> 2;          // 0..63: tile row being staged
    const int sk   = (t & 3) << 2;    // 0,4,8,12: k sub-offset
    const int tx   = t & 15, ty = t >> 4;

    const float* Arow = A + (size_t)(row0 + sr) * lda + sk;
    const bool bvalid = !NGUARD || (col0 + sr) < N;
    const float* Brow = Bw + (size_t)(bvalid ? (col0 + sr) : 0) * ldb + sk;

    float acc[4][4] = {};

    for (int k0 = 0; k0 < K; k0 += BK) {
        float4 av, bv;
        if (!NGUARD || (k0 + BK <= K)) {
            av = *(const float4*)(Arow + k0);
            bv = bvalid ? *(const float4*)(Brow + k0) : make_float4(0.f, 0.f, 0.f, 0.f);
        } else {
            float aa[4], bb[4];
            #pragma unroll
            for (int q = 0; q < 4; ++q) {
                const int kg = k0 + sk + q;
                aa[q] = (kg < K) ? Arow[k0 + q] : 0.f;
                bb[q] = (bvalid && kg < K) ? Brow[k0 + q] : 0.f;
            }
            av = make_float4(aa[0], aa[1], aa[2], aa[3]);
            bv = make_float4(bb[0], bb[1], bb[2], bb[3]);
        }
        __syncthreads();
        As[sk + 0][sr] = av.x; As[sk + 1][sr] = av.y;
        As[sk + 2][sr] = av.z; As[sk + 3][sr] = av.w;
        Bs[sk + 0][sr] = bv.x; Bs[sk + 1][sr] = bv.y;
        Bs[sk + 2][sr] = bv.z; Bs[sk + 3][sr] = bv.w;
        __syncthreads();
        #pragma unroll
        for (int kk = 0; kk < BK; ++kk) {
            const float4 a = *(const float4*)&As[kk][ty * 4];
            const float4 b = *(const float4*)&Bs[kk][tx * 4];
            const float a4[4] = {a.x, a.y, a.z, a.w};
            const float b4[4] = {b.x, b.y, b.z, b.w};
            #pragma unroll
            for (int i = 0; i < 4; ++i)
                #pragma unroll
                for (int j = 0; j < 4; ++j)
                    acc[i][j] = fmaf(a4[i], b4[j], acc[i][j]);
        }
    }

    #pragma unroll
    for (int i = 0; i < 4; ++i) {
        const int r = row0 + ty * 4 + i;
        if (NGUARD) {
            #pragma unroll
            for (int j = 0; j < 4; ++j) {
                const int c = col0 + tx * 4 + j;
                if (c < N) {
                    float v = acc[i][j] + (bias ? bias[c] : 0.f);
                    if (RELU) v = fmaxf(v, 0.f);
                    C[(size_t)r * ldc + c] = v;
                }
            }
        } else {
            const int c = col0 + tx * 4;
            float4 v;
            v.x = acc[i][0] + (bias ? bias[c + 0] : 0.f);
            v.y = acc[i][1] + (bias ? bias[c + 1] : 0.f);
            v.z = acc[i][2] + (bias ? bias[c + 2] : 0.f);
            v.w = acc[i][3] + (bias ? bias[c + 3] : 0.f);
            if (RELU) {
                v.x = fmaxf(v.x, 0.f); v.y = fmaxf(v.y, 0.f);
                v.z = fmaxf(v.z, 0.f); v.w = fmaxf(v.w, 0.f);
            }
            *(float4*)(C + (size_t)r * ldc + c) = v;
        }
    }
}

// ---------------------------------------------------------------------------
// Per-row (wave-per-row): argmax(logits), softmax, y = known ? onehot : softmax
// (written to Z cols 1024..1087, pad zeroed), z_q_x = codebook[argmax].
// ---------------------------------------------------------------------------
__global__ __launch_bounds__(256) void head_kernel(
    const float* __restrict__ logits,     // [B][43]
    const float* __restrict__ codebook,   // [43][500]
    const int* __restrict__ known_mask,
    const int* __restrict__ labels,
    float* __restrict__ zq_out,           // [B][500]
    float* __restrict__ Z)                // [B][1088], writes cols 1024..1087
{
    const int wave = threadIdx.x >> 6;
    const int lane = threadIdx.x & 63;
    const int row  = blockIdx.x * 4 + wave;

    const float* lrow = logits + (size_t)row * 43;
    const float v = (lane < 43) ? lrow[lane] : -INFINITY;

    // argmax (max value, first index on ties — matches np.argmax)
    float bvv = v; int bi = lane;
    #pragma unroll
    for (int off = 32; off; off >>= 1) {
        const float ov = __shfl_xor(bvv, off);
        const int   oi = __shfl_xor(bi, off);
        if (ov > bvv || (ov == bvv && oi < bi)) { bvv = ov; bi = oi; }
    }

    // softmax
    float e = (lane < 43) ? expf(v - bvv) : 0.f;
    float s = e;
    #pragma unroll
    for (int off = 32; off; off >>= 1) s += __shfl_xor(s, off);

    const int km  = known_mask[row];
    const int lab = labels[row];
    float y;
    if (lane < 43) y = km ? ((lane == lab) ? 1.f : 0.f) : (e / s);
    else           y = 0.f;   // zeros K-pad cols 1067..1087 too
    Z[(size_t)row * 1088 + 1024 + lane] = y;

    // z_q_x row copy
    const float* crow = codebook + (size_t)bi * 500;
    float* zrow = zq_out + (size_t)row * 500;
    for (int c = lane; c < 500; c += 64) zrow[c] = crow[c];
}

// ---------------------------------------------------------------------------
// sampled_z = mu + exp(0.5*logvar)*eps  → Z cols 0..1023
// kl partials → block reduce → atomicAdd(kl)/B
// ---------------------------------------------------------------------------
__global__ __launch_bounds__(256) void vae_sample(
    const float* __restrict__ ML,   // [B][2048]
    const float* __restrict__ eps,  // [B][1024]
    float* __restrict__ Z,          // [B][1088]
    float* __restrict__ kl_out)
{
    float klsum = 0.f;
    const int total = B_ROWS * 256;  // float4 chunks (1024/4 per row)
    for (int g = blockIdx.x * blockDim.x + threadIdx.x; g < total;
         g += gridDim.x * blockDim.x) {
        const int m = g >> 8;
        const int j = (g & 255) << 2;
        const float4 mu = *(const float4*)(ML + (size_t)m * 2048 + j);
        const float4 lv = *(const float4*)(ML + (size_t)m * 2048 + 1024 + j);
        const float4 ep = *(const float4*)(eps + (size_t)m * 1024 + j);
        float4 z;
        z.x = fmaf(expf(0.5f * lv.x), ep.x, mu.x);
        z.y = fmaf(expf(0.5f * lv.y), ep.y, mu.y);
        z.z = fmaf(expf(0.5f * lv.z), ep.z, mu.z);
        z.w = fmaf(expf(0.5f * lv.w), ep.w, mu.w);
        *(float4*)(Z + (size_t)m * 1088 + j) = z;
        klsum += 0.5f * ((expf(lv.x) + mu.x * mu.x - 1.f - lv.x)
                       + (expf(lv.y) + mu.y * mu.y - 1.f - lv.y)
                       + (expf(lv.z) + mu.z * mu.z - 1.f - lv.z)
                       + (expf(lv.w) + mu.w * mu.w - 1.f - lv.w));
    }
    __shared__ float wsum[4];
    const int lane = threadIdx.x & 63, wave = threadIdx.x >> 6;
    #pragma unroll
    for (int off = 32; off; off >>= 1) klsum += __shfl_xor(klsum, off);
    if (lane == 0) wsum[wave] = klsum;
    __syncthreads();
    if (threadIdx.x == 0)
        atomicAdd(kl_out, (wsum[0] + wsum[1] + wsum[2] + wsum[3]) * (1.0f / 16384.f));
}

// Wd [768][1067] → Wd_pad [768][1088], zero-padded (K-pad makes x_tilde GEMM
// K a multiple of 16 with 16B-aligned rows).
__global__ __launch_bounds__(256) void repack_wd(
    const float* __restrict__ Wd, float* __restrict__ Wdp)
{
    const int idx = blockIdx.x * 256 + threadIdx.x;
    if (idx >= 768 * 1088) return;
    const int n = idx / 1088;
    const int k = idx - n * 1088;
    Wdp[idx] = (k < 1067) ? Wd[(size_t)n * 1067 + k] : 0.f;
}

extern "C" void kernel_launch(void* const* d_in, const int* in_sizes, int n_in,
                              void* d_out, int out_size, void* d_ws, size_t ws_size,
                              hipStream_t stream) {
    const float* x        = (const float*)d_in[0];
    const int*   known    = (const int*)  d_in[1];
    const int*   labels   = (const int*)  d_in[2];
    const float* eps      = (const float*)d_in[3];
    const float* W_enc    = (const float*)d_in[4];
    const float* b_enc    = (const float*)d_in[5];
    const float* codebook = (const float*)d_in[6];
    const float* W1       = (const float*)d_in[7];
    const float* b1       = (const float*)d_in[8];
    const float* W2       = (const float*)d_in[9];
    const float* b2       = (const float*)d_in[10];
    const float* Wd       = (const float*)d_in[11];
    const float* bd       = (const float*)d_in[12];
    float* out = (float*)d_out;
    float* ws  = (float*)d_ws;

    float* h   = ws + WS_H;
    float* Z   = ws + WS_Z;
    float* ML  = ws + WS_ML;
    float* Wdp = ws + WS_WDP;

    hipMemsetAsync(out + KL_OFF, 0, sizeof(float), stream);

    const dim3 blk(256);
    // h = relu(x @ W1^T + b1)                          [16384,1024] K=768
    gemm_tn<true, false><<<dim3(1024 / TILE, B_ROWS / TILE), blk, 0, stream>>>(
        x, 768, W1, 768, b1, h, 1024, 1024, 768);
    // mu_logvar = h @ W2^T + b2                        [16384,2048] K=1024
    gemm_tn<false, false><<<dim3(2048 / TILE, B_ROWS / TILE), blk, 0, stream>>>(
        h, 1024, W2, 1024, b2, ML, 2048, 2048, 1024);
    // z_e_x = x @ W_enc^T + b_enc                      [16384,500] K=768
    gemm_tn<false, true><<<dim3(8, B_ROWS / TILE), blk, 0, stream>>>(
        x, 768, W_enc, 768, b_enc, out + ZE_OFF, 500, 500, 768);
    // logits = z_e_x @ codebook^T                      [16384,43] K=500
    gemm_tn<false, true><<<dim3(1, B_ROWS / TILE), blk, 0, stream>>>(
        out + ZE_OFF, 500, codebook, 500, nullptr, out + LOG_OFF, 43, 43, 500);
    // argmax / softmax / y / z_q_x
    head_kernel<<<B_ROWS / 4, blk, 0, stream>>>(
        out + LOG_OFF, codebook, known, labels, out + ZQ_OFF, Z);
    // sampled_z + kl
    vae_sample<<<2048, blk, 0, stream>>>(ML, eps, Z, out + KL_OFF);
    // Wd repack (pad K 1067→1088)
    repack_wd<<<(768 * 1088 + 255) / 256, blk, 0, stream>>>(Wd, Wdp);
    // x_tilde = [sampled_z | y] @ Wd^T + bd            [16384,768] K=1088
    gemm_tn<false, false><<<dim3(768 / TILE, B_ROWS / TILE), blk, 0, stream>>>(
        Z, 1088, Wdp, 1088, bd, out + X_TILDE_OFF, 768, 768, 1088);
}

// Round 2
// 701.800 us; speedup vs baseline: 2.9245x; 2.9245x over previous
//
#include <hip/hip_runtime.h>
#include <hip/hip_bf16.h>
#include <math.h>

// ---------------------------------------------------------------------------
// VQVAE forward. bf16-MFMA for {h, mu_logvar, x_tilde}; fp32 for the
// argmax-critical {z_e_x, logits} path.
// Outputs: x_tilde[16384,768], z_e_x[16384,500], z_q_x[16384,500],
// logits[16384,43], kl_div[1]
// ---------------------------------------------------------------------------

#define B_ROWS 16384
#define TILE 64
#define BK 16

typedef __attribute__((ext_vector_type(8))) short bf16x8;
typedef __attribute__((ext_vector_type(4))) float f32x4;

constexpr size_t X_TILDE_OFF = 0;
constexpr size_t ZE_OFF      = 12582912;
constexpr size_t ZQ_OFF      = 20774912;
constexpr size_t LOG_OFF     = 28966912;
constexpr size_t KL_OFF      = 29671424;

// ws byte offsets. xb (bf16 x copy) aliases Zb: xb's last read (h GEMM)
// precedes all Zb writes (head_kernel / vae_sample) in stream order.
constexpr size_t WS_ZB  = 0;            // [16384][1088] bf16 (35.65 MB) / xb [16384][768] bf16
constexpr size_t WS_HB  = 35651584;     // [16384][1024] bf16 (33.55 MB)
constexpr size_t WS_MLB = 69206016;     // [16384][2048] bf16 (67.1 MB)
constexpr size_t WS_W1B = 136314880;    // [1024][768]  bf16
constexpr size_t WS_W2B = 137887744;    // [2048][1024] bf16
constexpr size_t WS_WDB = 142082048;    // [768][1088]  bf16

__device__ __forceinline__ unsigned short f2b(float f) {
    unsigned u = __builtin_bit_cast(unsigned, f);
    return (unsigned short)((u + 0x7FFFu + ((u >> 16) & 1u)) >> 16);
}
__device__ __forceinline__ float b2f(unsigned short u) {
    return __uint_as_float(((unsigned)u) << 16);
}

__device__ __forceinline__ void stage16(const void* g, void* l) {
    __builtin_amdgcn_global_load_lds(
        (const __attribute__((address_space(1))) void*)g,
        (__attribute__((address_space(3))) void*)l, 16, 0, 0);
}

// ---------------------------------------------------------------------------
// bf16 MFMA GEMM (m97 structure): C[M x N] = act(A @ Bw^T + bias)
// A [M][K] bf16, Bw [N][K] bf16 (both K-contiguous), bias f32.
// 128x128 tile, BK=32, 4 waves, 4x4 16x16x32 fragments per wave.
// Requires: M%128==0, N%128==0, K%32==0, rows 16B-aligned.
// ---------------------------------------------------------------------------
template<bool RELU, bool OUT_BF16>
__global__ __launch_bounds__(256) void gemm_bf16(
    const unsigned short* __restrict__ A,
    const unsigned short* __restrict__ Bw,
    const float* __restrict__ bias,
    void* __restrict__ Cv,
    int lda, int ldb, int ldc, int K)
{
    __shared__ short As[128 * 32];
    __shared__ short Bs[128 * 32];
    const int t  = threadIdx.x;
    const int w  = t >> 6, l = t & 63;
    const int row0 = blockIdx.y * 128;
    const int col0 = blockIdx.x * 128;
    const int wr = (w >> 1) * 64, wc = (w & 1) * 64;

    // staging: chunk ci = c*256 + t covers LDS bytes [ci*16, ci*16+16);
    // tile row = ci>>2, k sub-offset = (ci&3)*8 elements.
    const unsigned short* a0 = A  + (size_t)(row0 + (t >> 2)) * lda + ((t & 3) << 3);
    const unsigned short* b0 = Bw + (size_t)(col0 + (t >> 2)) * ldb + ((t & 3) << 3);
    const size_t aStep = (size_t)64 * lda;
    const size_t bStep = (size_t)64 * ldb;
    short* lA0 = As + t * 8;       short* lA1 = As + (256 + t) * 8;
    short* lB0 = Bs + t * 8;       short* lB1 = Bs + (256 + t) * 8;

    f32x4 acc[4][4] = {};
    const int fr = l & 15;
    const int fk = (l >> 4) << 3;   // k element offset for A/B frags

    for (int k0 = 0; k0 < K; k0 += 32) {
        stage16(a0 + k0, lA0);
        stage16(a0 + aStep + k0, lA1);
        stage16(b0 + k0, lB0);
        stage16(b0 + bStep + k0, lB1);
        __syncthreads();            // drains vmcnt + barrier
        bf16x8 am[4], bn[4];
        #pragma unroll
        for (int i = 0; i < 4; ++i)
            am[i] = *(const bf16x8*)&As[(wr + i * 16 + fr) * 32 + fk];
        #pragma unroll
        for (int j = 0; j < 4; ++j)
            bn[j] = *(const bf16x8*)&Bs[(wc + j * 16 + fr) * 32 + fk];
        #pragma unroll
        for (int i = 0; i < 4; ++i)
            #pragma unroll
            for (int j = 0; j < 4; ++j)
                acc[i][j] = __builtin_amdgcn_mfma_f32_16x16x32_bf16(
                    am[i], bn[j], acc[i][j], 0, 0, 0);
        __syncthreads();            // protect LDS before next stage
    }

    // C/D layout: col = lane&15, row = (lane>>4)*4 + reg   [m89/m91]
    const int fq = (l >> 4) << 2;
    #pragma unroll
    for (int i = 0; i < 4; ++i) {
        #pragma unroll
        for (int j = 0; j < 4; ++j) {
            const int c = col0 + wc + j * 16 + fr;
            const int r = row0 + wr + i * 16 + fq;
            const float bv = bias[c];
            #pragma unroll
            for (int q = 0; q < 4; ++q) {
                float v = acc[i][j][q] + bv;
                if (RELU) v = fmaxf(v, 0.f);
                if (OUT_BF16)
                    ((unsigned short*)Cv)[(size_t)(r + q) * ldc + c] = f2b(v);
                else
                    ((float*)Cv)[(size_t)(r + q) * ldc + c] = v;
            }
        }
    }
}

// ---------------------------------------------------------------------------
// fp32 GEMM (argmax-critical path): C = A @ Bw^T + bias
// ---------------------------------------------------------------------------
template<bool RELU, bool NGUARD>
__global__ __launch_bounds__(256) void gemm_tn(
    const float* __restrict__ A, int lda,
    const float* __restrict__ Bw, int ldb,
    const float* __restrict__ bias,
    float* __restrict__ C, int ldc, int N, int K)
{
    __shared__ float As[BK][TILE + 4];
    __shared__ float Bs[BK][TILE + 4];
    const int t    = threadIdx.x;
    const int bn   = blockIdx.x, bm = blockIdx.y;
    const int row0 = bm * TILE, col0 = bn * TILE;
    const int sr   = t >> 2;
    const int sk   = (t & 3) << 2;
    const int tx   = t & 15, ty = t >> 4;

    const float* Arow = A + (size_t)(row0 + sr) * lda + sk;
    const bool bvalid = !NGUARD || (col0 + sr) < N;
    const float* Brow = Bw + (size_t)(bvalid ? (col0 + sr) : 0) * ldb + sk;

    float acc[4][4] = {};

    for (int k0 = 0; k0 < K; k0 += BK) {
        float4 av, bv;
        if (!NGUARD || (k0 + BK <= K)) {
            av = *(const float4*)(Arow + k0);
            bv = bvalid ? *(const float4*)(Brow + k0) : make_float4(0.f, 0.f, 0.f, 0.f);
        } else {
            float aa[4], bb[4];
            #pragma unroll
            for (int q = 0; q < 4; ++q) {
                const int kg = k0 + sk + q;
                aa[q] = (kg < K) ? Arow[k0 + q] : 0.f;
                bb[q] = (bvalid && kg < K) ? Brow[k0 + q] : 0.f;
            }
            av = make_float4(aa[0], aa[1], aa[2], aa[3]);
            bv = make_float4(bb[0], bb[1], bb[2], bb[3]);
        }
        __syncthreads();
        As[sk + 0][sr] = av.x; As[sk + 1][sr] = av.y;
        As[sk + 2][sr] = av.z; As[sk + 3][sr] = av.w;
        Bs[sk + 0][sr] = bv.x; Bs[sk + 1][sr] = bv.y;
        Bs[sk + 2][sr] = bv.z; Bs[sk + 3][sr] = bv.w;
        __syncthreads();
        #pragma unroll
        for (int kk = 0; kk < BK; ++kk) {
            const float4 a = *(const float4*)&As[kk][ty * 4];
            const float4 b = *(const float4*)&Bs[kk][tx * 4];
            const float a4[4] = {a.x, a.y, a.z, a.w};
            const float b4[4] = {b.x, b.y, b.z, b.w};
            #pragma unroll
            for (int i = 0; i < 4; ++i)
                #pragma unroll
                for (int j = 0; j < 4; ++j)
                    acc[i][j] = fmaf(a4[i], b4[j], acc[i][j]);
        }
    }

    #pragma unroll
    for (int i = 0; i < 4; ++i) {
        const int r = row0 + ty * 4 + i;
        if (NGUARD) {
            #pragma unroll
            for (int j = 0; j < 4; ++j) {
                const int c = col0 + tx * 4 + j;
                if (c < N) {
                    float v = acc[i][j] + (bias ? bias[c] : 0.f);
                    if (RELU) v = fmaxf(v, 0.f);
                    C[(size_t)r * ldc + c] = v;
                }
            }
        } else {
            const int c = col0 + tx * 4;
            float4 v;
            v.x = acc[i][0] + (bias ? bias[c + 0] : 0.f);
            v.y = acc[i][1] + (bias ? bias[c + 1] : 0.f);
            v.z = acc[i][2] + (bias ? bias[c + 2] : 0.f);
            v.w = acc[i][3] + (bias ? bias[c + 3] : 0.f);
            if (RELU) {
                v.x = fmaxf(v.x, 0.f); v.y = fmaxf(v.y, 0.f);
                v.z = fmaxf(v.z, 0.f); v.w = fmaxf(v.w, 0.f);
            }
            *(float4*)(C + (size_t)r * ldc + c) = v;
        }
    }
}

// ---------------------------------------------------------------------------
// Per-row head: argmax/softmax of logits, y (bf16) into Zb cols 1024..1087,
// z_q_x = codebook[argmax] (f32).
// ---------------------------------------------------------------------------
__global__ __launch_bounds__(256) void head_kernel(
    const float* __restrict__ logits,
    const float* __restrict__ codebook,
    const int* __restrict__ known_mask,
    const int* __restrict__ labels,
    float* __restrict__ zq_out,
    unsigned short* __restrict__ Zb)
{
    const int wave = threadIdx.x >> 6;
    const int lane = threadIdx.x & 63;
    const int row  = blockIdx.x * 4 + wave;

    const float* lrow = logits + (size_t)row * 43;
    const float v = (lane < 43) ? lrow[lane] : -INFINITY;

    float bvv = v; int bi = lane;
    #pragma unroll
    for (int off = 32; off; off >>= 1) {
        const float ov = __shfl_xor(bvv, off);
        const int   oi = __shfl_xor(bi, off);
        if (ov > bvv || (ov == bvv && oi < bi)) { bvv = ov; bi = oi; }
    }

    float e = (lane < 43) ? expf(v - bvv) : 0.f;
    float s = e;
    #pragma unroll
    for (int off = 32; off; off >>= 1) s += __shfl_xor(s, off);

    const int km  = known_mask[row];
    const int lab = labels[row];
    float y;
    if (lane < 43) y = km ? ((lane == lab) ? 1.f : 0.f) : (e / s);
    else           y = 0.f;   // zeros K-pad cols 1067..1087
    Zb[(size_t)row * 1088 + 1024 + lane] = f2b(y);

    const float* crow = codebook + (size_t)bi * 500;
    float* zrow = zq_out + (size_t)row * 500;
    for (int c = lane; c < 500; c += 64) zrow[c] = crow[c];
}

// ---------------------------------------------------------------------------
// sampled_z (bf16) -> Zb cols 0..1023; kl partials -> atomicAdd
// ---------------------------------------------------------------------------
__global__ __launch_bounds__(256) void vae_sample(
    const unsigned short* __restrict__ MLb,  // [B][2048] bf16
    const float* __restrict__ eps,           // [B][1024] f32
    unsigned short* __restrict__ Zb,         // [B][1088] bf16
    float* __restrict__ kl_out)
{
    float klsum = 0.f;
    const int total = B_ROWS * 128;  // 8-elem chunks
    for (int g = blockIdx.x * blockDim.x + threadIdx.x; g < total;
         g += gridDim.x * blockDim.x) {
        const int m = g >> 7;
        const int j = (g & 127) << 3;
        const bf16x8 muv = *(const bf16x8*)(MLb + (size_t)m * 2048 + j);
        const bf16x8 lvv = *(const bf16x8*)(MLb + (size_t)m * 2048 + 1024 + j);
        const float4 e0 = *(const float4*)(eps + (size_t)m * 1024 + j);
        const float4 e1 = *(const float4*)(eps + (size_t)m * 1024 + j + 4);
        const float ep[8] = {e0.x, e0.y, e0.z, e0.w, e1.x, e1.y, e1.z, e1.w};
        bf16x8 zv;
        #pragma unroll
        for (int q = 0; q < 8; ++q) {
            const float mu = b2f((unsigned short)muv[q]);
            const float lv = b2f((unsigned short)lvv[q]);
            const float z  = fmaf(expf(0.5f * lv), ep[q], mu);
            zv[q] = (short)f2b(z);
            klsum += 0.5f * (expf(lv) + mu * mu - 1.f - lv);
        }
        *(bf16x8*)(Zb + (size_t)m * 1088 + j) = zv;
    }
    __shared__ float wsum[4];
    const int lane = threadIdx.x & 63, wave = threadIdx.x >> 6;
    #pragma unroll
    for (int off = 32; off; off >>= 1) klsum += __shfl_xor(klsum, off);
    if (lane == 0) wsum[wave] = klsum;
    __syncthreads();
    if (threadIdx.x == 0)
        atomicAdd(kl_out, (wsum[0] + wsum[1] + wsum[2] + wsum[3]) * (1.0f / 16384.f));
}

// f32 -> bf16 (RNE), n % 4 == 0
__global__ __launch_bounds__(256) void conv_bf16(
    const float* __restrict__ in, unsigned short* __restrict__ out, int n)
{
    const int i = (blockIdx.x * 256 + threadIdx.x) * 4;
    if (i >= n) return;
    const float4 v = *(const float4*)(in + i);
    ushort4 o;
    o.x = f2b(v.x); o.y = f2b(v.y); o.z = f2b(v.z); o.w = f2b(v.w);
    *(ushort4*)(out + i) = o;
}

// Wd [768][1067] f32 -> [768][1088] bf16, zero K-pad
__global__ __launch_bounds__(256) void repack_wd(
    const float* __restrict__ Wd, unsigned short* __restrict__ Wdb)
{
    const int idx = blockIdx.x * 256 + threadIdx.x;
    if (idx >= 768 * 1088) return;
    const int n = idx / 1088;
    const int k = idx - n * 1088;
    Wdb[idx] = (k < 1067) ? f2b(Wd[(size_t)n * 1067 + k]) : 0;
}

extern "C" void kernel_launch(void* const* d_in, const int* in_sizes, int n_in,
                              void* d_out, int out_size, void* d_ws, size_t ws_size,
                              hipStream_t stream) {
    const float* x        = (const float*)d_in[0];
    const int*   known    = (const int*)  d_in[1];
    const int*   labels   = (const int*)  d_in[2];
    const float* eps      = (const float*)d_in[3];
    const float* W_enc    = (const float*)d_in[4];
    const float* b_enc    = (const float*)d_in[5];
    const float* codebook = (const float*)d_in[6];
    const float* W1       = (const float*)d_in[7];
    const float* b1       = (const float*)d_in[8];
    const float* W2       = (const float*)d_in[9];
    const float* b2       = (const float*)d_in[10];
    const float* Wd       = (const float*)d_in[11];
    const float* bd       = (const float*)d_in[12];
    float* out = (float*)d_out;
    char*  ws  = (char*)d_ws;

    unsigned short* xb  = (unsigned short*)(ws + WS_ZB);   // aliased with Zb
    unsigned short* Zb  = (unsigned short*)(ws + WS_ZB);
    unsigned short* hb  = (unsigned short*)(ws + WS_HB);
    unsigned short* MLb = (unsigned short*)(ws + WS_MLB);
    unsigned short* W1b = (unsigned short*)(ws + WS_W1B);
    unsigned short* W2b = (unsigned short*)(ws + WS_W2B);
    unsigned short* Wdb = (unsigned short*)(ws + WS_WDB);

    hipMemsetAsync(out + KL_OFF, 0, sizeof(float), stream);

    const dim3 blk(256);
    // conversions
    conv_bf16<<<(16384 * 768 / 4 + 255) / 256, blk, 0, stream>>>(x, xb, 16384 * 768);
    conv_bf16<<<(1024 * 768 / 4 + 255) / 256, blk, 0, stream>>>(W1, W1b, 1024 * 768);
    conv_bf16<<<(2048 * 1024 / 4 + 255) / 256, blk, 0, stream>>>(W2, W2b, 2048 * 1024);
    repack_wd<<<(768 * 1088 + 255) / 256, blk, 0, stream>>>(Wd, Wdb);

    // h = relu(x @ W1^T + b1)        [16384,1024] bf16, K=768
    gemm_bf16<true, true><<<dim3(1024 / 128, B_ROWS / 128), blk, 0, stream>>>(
        xb, W1b, b1, hb, 768, 768, 1024, 768);
    // mu_logvar = h @ W2^T + b2      [16384,2048] bf16, K=1024
    gemm_bf16<false, true><<<dim3(2048 / 128, B_ROWS / 128), blk, 0, stream>>>(
        hb, W2b, b2, MLb, 1024, 1024, 2048, 1024);
    // z_e_x = x @ W_enc^T + b_enc    [16384,500] f32, K=768
    gemm_tn<false, true><<<dim3(8, B_ROWS / TILE), blk, 0, stream>>>(
        x, 768, W_enc, 768, b_enc, out + ZE_OFF, 500, 500, 768);
    // logits = z_e_x @ codebook^T    [16384,43] f32, K=500
    gemm_tn<false, true><<<dim3(1, B_ROWS / TILE), blk, 0, stream>>>(
        out + ZE_OFF, 500, codebook, 500, nullptr, out + LOG_OFF, 43, 43, 500);
    // head: argmax/softmax/y/z_q_x
    head_kernel<<<B_ROWS / 4, blk, 0, stream>>>(
        out + LOG_OFF, codebook, known, labels, out + ZQ_OFF, Zb);
    // sampled_z + kl
    vae_sample<<<2048, blk, 0, stream>>>(MLb, eps, Zb, out + KL_OFF);
    // x_tilde = [sampled_z | y] @ Wd^T + bd   [16384,768] f32, K=1088
    gemm_bf16<false, false><<<dim3(768 / 128, B_ROWS / 128), blk, 0, stream>>>(
        Zb, Wdb, bd, out + X_TILDE_OFF, 1088, 1088, 768, 1088);
}

// Round 3
// 642.332 us; speedup vs baseline: 3.1952x; 1.0926x over previous
//
#include <hip/hip_runtime.h>
#include <hip/hip_bf16.h>
#include <math.h>

// ---------------------------------------------------------------------------
// VQVAE forward. bf16-MFMA for {h, mu_logvar, x_tilde}; split-bf16 (bf16x3)
// MFMA for the argmax-critical {z_e_x, logits} path with fp64 repair of
// near-tie argmax rows.
// Outputs: x_tilde[16384,768], z_e_x[16384,500], z_q_x[16384,500],
// logits[16384,43], kl_div[1]
// ---------------------------------------------------------------------------

#define B_ROWS 16384

typedef __attribute__((ext_vector_type(8))) short bf16x8;
typedef __attribute__((ext_vector_type(4))) float f32x4;

constexpr size_t X_TILDE_OFF = 0;
constexpr size_t ZE_OFF      = 12582912;
constexpr size_t ZQ_OFF      = 20774912;
constexpr size_t LOG_OFF     = 28966912;
constexpr size_t KL_OFF      = 29671424;

// ws byte offsets (total ~196.3 MB, fits the >=209 MB ws proven in round 0)
constexpr size_t WS_XH  = 0;            // [16384][768]  bf16 hi(x)
constexpr size_t WS_XL  = 25165824;     // [16384][768]  bf16 lo(x)
constexpr size_t WS_ZB  = 50331648;     // [16384][1088] bf16 concat [z|y]
constexpr size_t WS_HB  = 85983232;     // [16384][1024] bf16 h
constexpr size_t WS_MLB = 119537664;    // [16384][2048] bf16 mu_logvar
constexpr size_t WS_W1B = 186646528;    // [1024][768]  bf16
constexpr size_t WS_W2B = 188219392;    // [2048][1024] bf16
constexpr size_t WS_WDB = 192413696;    // [768][1088]  bf16
constexpr size_t WS_WEH = 194084864;    // [512][768]   bf16 hi(W_enc), rows 500..511 zero
constexpr size_t WS_WEL = 194871296;    // [512][768]   bf16 lo(W_enc)
constexpr size_t WS_CBH = 195657728;    // [128][768]   bf16 hi(cbW), rows 43..127 zero
constexpr size_t WS_CBL = 195854336;    // [128][768]   bf16 lo(cbW)
constexpr size_t WS_CBD = 196050944;    // [43][768]    f64 cbW (repair)
constexpr size_t WS_LBF = 196315136;    // [128]        f32 logits bias (zero-padded)
constexpr size_t WS_LBD = 196315648;    // [43]         f64 logits bias

__device__ __forceinline__ unsigned short f2b(float f) {
    unsigned u = __builtin_bit_cast(unsigned, f);
    return (unsigned short)((u + 0x7FFFu + ((u >> 16) & 1u)) >> 16);
}
__device__ __forceinline__ float b2f(unsigned short u) {
    return __uint_as_float(((unsigned)u) << 16);
}

__device__ __forceinline__ void stage16(const void* g, void* l) {
    __builtin_amdgcn_global_load_lds(
        (const __attribute__((address_space(1))) void*)g,
        (__attribute__((address_space(3))) void*)l, 16, 0, 0);
}

// ---------------------------------------------------------------------------
// bf16 MFMA GEMM (m97 structure): C = act(A @ Bw^T + bias)
// 128x128 tile, BK=32, 4 waves, 4x4 16x16x32 fragments.
// ---------------------------------------------------------------------------
template<bool RELU, bool OUT_BF16>
__global__ __launch_bounds__(256) void gemm_bf16(
    const unsigned short* __restrict__ A,
    const unsigned short* __restrict__ Bw,
    const float* __restrict__ bias,
    void* __restrict__ Cv,
    int lda, int ldb, int ldc, int K)
{
    __shared__ short As[128 * 32];
    __shared__ short Bs[128 * 32];
    const int t  = threadIdx.x;
    const int w  = t >> 6, l = t & 63;
    const int row0 = blockIdx.y * 128;
    const int col0 = blockIdx.x * 128;
    const int wr = (w >> 1) * 64, wc = (w & 1) * 64;

    const unsigned short* a0 = A  + (size_t)(row0 + (t >> 2)) * lda + ((t & 3) << 3);
    const unsigned short* b0 = Bw + (size_t)(col0 + (t >> 2)) * ldb + ((t & 3) << 3);
    const size_t aStep = (size_t)64 * lda;
    const size_t bStep = (size_t)64 * ldb;
    short* lA0 = As + t * 8;       short* lA1 = As + (256 + t) * 8;
    short* lB0 = Bs + t * 8;       short* lB1 = Bs + (256 + t) * 8;

    f32x4 acc[4][4] = {};
    const int fr = l & 15;
    const int fk = (l >> 4) << 3;

    for (int k0 = 0; k0 < K; k0 += 32) {
        stage16(a0 + k0, lA0);
        stage16(a0 + aStep + k0, lA1);
        stage16(b0 + k0, lB0);
        stage16(b0 + bStep + k0, lB1);
        __syncthreads();
        bf16x8 am[4], bn[4];
        #pragma unroll
        for (int i = 0; i < 4; ++i)
            am[i] = *(const bf16x8*)&As[(wr + i * 16 + fr) * 32 + fk];
        #pragma unroll
        for (int j = 0; j < 4; ++j)
            bn[j] = *(const bf16x8*)&Bs[(wc + j * 16 + fr) * 32 + fk];
        #pragma unroll
        for (int i = 0; i < 4; ++i)
            #pragma unroll
            for (int j = 0; j < 4; ++j)
                acc[i][j] = __builtin_amdgcn_mfma_f32_16x16x32_bf16(
                    am[i], bn[j], acc[i][j], 0, 0, 0);
        __syncthreads();
    }

    const int fq = (l >> 4) << 2;
    #pragma unroll
    for (int i = 0; i < 4; ++i) {
        #pragma unroll
        for (int j = 0; j < 4; ++j) {
            const int c = col0 + wc + j * 16 + fr;
            const int r = row0 + wr + i * 16 + fq;
            const float bv = bias[c];
            #pragma unroll
            for (int q = 0; q < 4; ++q) {
                float v = acc[i][j][q] + bv;
                if (RELU) v = fmaxf(v, 0.f);
                if (OUT_BF16)
                    ((unsigned short*)Cv)[(size_t)(r + q) * ldc + c] = f2b(v);
                else
                    ((float*)Cv)[(size_t)(r + q) * ldc + c] = v;
            }
        }
    }
}

// ---------------------------------------------------------------------------
// split-bf16 GEMM: C = (Ah+Al) @ (Bh+Bl)^T + bias, dropping the lo*lo term.
// acc += Ah*Bh + Al*Bh + Ah*Bl  (each a 16x16x32 MFMA). fp32 out.
// ---------------------------------------------------------------------------
template<bool NGUARD>
__global__ __launch_bounds__(256) void gemm_bf16x3(
    const unsigned short* __restrict__ Ah,
    const unsigned short* __restrict__ Al,
    const unsigned short* __restrict__ Bh,
    const unsigned short* __restrict__ Bl,
    const float* __restrict__ bias,
    float* __restrict__ C,
    int lda, int ldb, int ldc, int N, int K)
{
    __shared__ short sAh[128 * 32];
    __shared__ short sAl[128 * 32];
    __shared__ short sBh[128 * 32];
    __shared__ short sBl[128 * 32];
    const int t  = threadIdx.x;
    const int w  = t >> 6, l = t & 63;
    const int row0 = blockIdx.y * 128;
    const int col0 = blockIdx.x * 128;
    const int wr = (w >> 1) * 64, wc = (w & 1) * 64;

    const size_t aoff  = (size_t)(row0 + (t >> 2)) * lda + ((t & 3) << 3);
    const size_t boff  = (size_t)(col0 + (t >> 2)) * ldb + ((t & 3) << 3);
    const size_t aStep = (size_t)64 * lda;
    const size_t bStep = (size_t)64 * ldb;
    const int l0 = t * 8, l1 = (256 + t) * 8;

    f32x4 acc[4][4] = {};
    const int fr = l & 15;
    const int fk = (l >> 4) << 3;

    for (int k0 = 0; k0 < K; k0 += 32) {
        stage16(Ah + aoff + k0,         sAh + l0);
        stage16(Ah + aoff + aStep + k0, sAh + l1);
        stage16(Al + aoff + k0,         sAl + l0);
        stage16(Al + aoff + aStep + k0, sAl + l1);
        stage16(Bh + boff + k0,         sBh + l0);
        stage16(Bh + boff + bStep + k0, sBh + l1);
        stage16(Bl + boff + k0,         sBl + l0);
        stage16(Bl + boff + bStep + k0, sBl + l1);
        __syncthreads();
        bf16x8 ah[4], al[4], bh[4], bl[4];
        #pragma unroll
        for (int i = 0; i < 4; ++i) {
            ah[i] = *(const bf16x8*)&sAh[(wr + i * 16 + fr) * 32 + fk];
            al[i] = *(const bf16x8*)&sAl[(wr + i * 16 + fr) * 32 + fk];
        }
        #pragma unroll
        for (int j = 0; j < 4; ++j) {
            bh[j] = *(const bf16x8*)&sBh[(wc + j * 16 + fr) * 32 + fk];
            bl[j] = *(const bf16x8*)&sBl[(wc + j * 16 + fr) * 32 + fk];
        }
        #pragma unroll
        for (int i = 0; i < 4; ++i)
            #pragma unroll
            for (int j = 0; j < 4; ++j) {
                acc[i][j] = __builtin_amdgcn_mfma_f32_16x16x32_bf16(
                    ah[i], bh[j], acc[i][j], 0, 0, 0);
                acc[i][j] = __builtin_amdgcn_mfma_f32_16x16x32_bf16(
                    al[i], bh[j], acc[i][j], 0, 0, 0);
                acc[i][j] = __builtin_amdgcn_mfma_f32_16x16x32_bf16(
                    ah[i], bl[j], acc[i][j], 0, 0, 0);
            }
        __syncthreads();
    }

    const int fq = (l >> 4) << 2;
    #pragma unroll
    for (int i = 0; i < 4; ++i) {
        #pragma unroll
        for (int j = 0; j < 4; ++j) {
            const int c = col0 + wc + j * 16 + fr;
            if (!NGUARD || c < N) {
                const int r = row0 + wr + i * 16 + fq;
                const float bv = bias[c];
                #pragma unroll
                for (int q = 0; q < 4; ++q)
                    C[(size_t)(r + q) * ldc + c] = acc[i][j][q] + bv;
            }
        }
    }
}

// ---------------------------------------------------------------------------
// cbW = codebook @ W_enc  [43][768], fp64 + bf16 hi/lo split (rows padded to
// 128 with zeros); lb = codebook @ b_enc.
// ---------------------------------------------------------------------------
__global__ __launch_bounds__(256) void cbw_kernel(
    const float* __restrict__ W_enc,    // [500][768]
    const float* __restrict__ cb,       // [43][500]
    const float* __restrict__ b_enc,    // [500]
    double* __restrict__ cbWd,          // [43][768]
    unsigned short* __restrict__ cbWh,  // [128][768]
    unsigned short* __restrict__ cbWl,  // [128][768]
    float* __restrict__ lbf,            // [128]
    double* __restrict__ lbd)           // [43]
{
    const int j = blockIdx.x;   // 0..127
    const int t = threadIdx.x;  // 256
    if (j >= 43) {
        for (int d = t; d < 768; d += 256) {
            cbWh[(size_t)j * 768 + d] = 0;
            cbWl[(size_t)j * 768 + d] = 0;
        }
        if (t == 0) lbf[j] = 0.f;
        return;
    }
    double acc[3] = {0.0, 0.0, 0.0};
    for (int k = 0; k < 500; ++k) {
        const double c = (double)cb[(size_t)j * 500 + k];
        acc[0] = fma(c, (double)W_enc[(size_t)k * 768 + t],       acc[0]);
        acc[1] = fma(c, (double)W_enc[(size_t)k * 768 + t + 256], acc[1]);
        acc[2] = fma(c, (double)W_enc[(size_t)k * 768 + t + 512], acc[2]);
    }
    #pragma unroll
    for (int q = 0; q < 3; ++q) {
        const int d = t + q * 256;
        const double v = acc[q];
        cbWd[(size_t)j * 768 + d] = v;
        const float f = (float)v;
        const unsigned short h = f2b(f);
        cbWh[(size_t)j * 768 + d] = h;
        cbWl[(size_t)j * 768 + d] = f2b(f - b2f(h));
    }
    if (t == 0) {
        double s = 0.0;
        for (int k = 0; k < 500; ++k)
            s = fma((double)cb[(size_t)j * 500 + k], (double)b_enc[k], s);
        lbd[j] = s;
        lbf[j] = (float)s;
    }
}

// ---------------------------------------------------------------------------
// Head: argmax of logits with fp64 repair for near-ties (gap < 1e-3),
// softmax, y (bf16) into Zb cols 1024..1087, z_q_x = codebook[argmax].
// ---------------------------------------------------------------------------
__global__ __launch_bounds__(256) void head_kernel(
    const float* __restrict__ logits,     // [B][43]
    const float* __restrict__ codebook,   // [43][500]
    const int* __restrict__ known_mask,
    const int* __restrict__ labels,
    const float* __restrict__ x,          // [B][768]
    const double* __restrict__ cbWd,      // [43][768]
    const double* __restrict__ lbd,       // [43]
    float* __restrict__ zq_out,
    unsigned short* __restrict__ Zb)
{
    const int wave = threadIdx.x >> 6;
    const int lane = threadIdx.x & 63;
    const int row  = blockIdx.x * 4 + wave;

    const float* lrow = logits + (size_t)row * 43;
    const float v = (lane < 43) ? lrow[lane] : -INFINITY;

    // argmax (first index on ties, matches np.argmax)
    float bvv = v; int bi = lane;
    #pragma unroll
    for (int off = 32; off; off >>= 1) {
        const float ov = __shfl_xor(bvv, off);
        const int   oi = __shfl_xor(bi, off);
        if (ov > bvv || (ov == bvv && oi < bi)) { bvv = ov; bi = oi; }
    }
    // second max → top-2 gap
    float v2 = (lane == bi) ? -INFINITY : v;
    #pragma unroll
    for (int off = 32; off; off >>= 1) v2 = fmaxf(v2, __shfl_xor(v2, off));

    int idx = bi;
    if (bvv - v2 < 1e-3f) {   // near-tie: fp64 recompute (wave-uniform branch)
        double dv = -1.0e300;
        if (lane < 43) {
            double s = lbd[lane];
            const float* xr = x + (size_t)row * 768;
            const double* wrow = cbWd + (size_t)lane * 768;
            for (int d = 0; d < 768; ++d)
                s = fma((double)xr[d], wrow[d], s);
            dv = s;
        }
        double bdv = dv; int bj = lane;
        #pragma unroll
        for (int off = 32; off; off >>= 1) {
            const double ov = __shfl_xor(bdv, off);
            const int    oi = __shfl_xor(bj, off);
            if (ov > bdv || (ov == bdv && oi < bj)) { bdv = ov; bj = oi; }
        }
        idx = bj;
    }

    // softmax (fp32 logits)
    float e = (lane < 43) ? expf(v - bvv) : 0.f;
    float s = e;
    #pragma unroll
    for (int off = 32; off; off >>= 1) s += __shfl_xor(s, off);

    const int km  = known_mask[row];
    const int lab = labels[row];
    float y;
    if (lane < 43) y = km ? ((lane == lab) ? 1.f : 0.f) : (e / s);
    else           y = 0.f;   // zeros K-pad cols 1067..1087
    Zb[(size_t)row * 1088 + 1024 + lane] = f2b(y);

    const float* crow = codebook + (size_t)idx * 500;
    float* zrow = zq_out + (size_t)row * 500;
    for (int c = lane; c < 500; c += 64) zrow[c] = crow[c];
}

// ---------------------------------------------------------------------------
// sampled_z (bf16) -> Zb cols 0..1023; kl partials -> atomicAdd
// ---------------------------------------------------------------------------
__global__ __launch_bounds__(256) void vae_sample(
    const unsigned short* __restrict__ MLb,
    const float* __restrict__ eps,
    unsigned short* __restrict__ Zb,
    float* __restrict__ kl_out)
{
    float klsum = 0.f;
    const int total = B_ROWS * 128;
    for (int g = blockIdx.x * blockDim.x + threadIdx.x; g < total;
         g += gridDim.x * blockDim.x) {
        const int m = g >> 7;
        const int j = (g & 127) << 3;
        const bf16x8 muv = *(const bf16x8*)(MLb + (size_t)m * 2048 + j);
        const bf16x8 lvv = *(const bf16x8*)(MLb + (size_t)m * 2048 + 1024 + j);
        const float4 e0 = *(const float4*)(eps + (size_t)m * 1024 + j);
        const float4 e1 = *(const float4*)(eps + (size_t)m * 1024 + j + 4);
        const float ep[8] = {e0.x, e0.y, e0.z, e0.w, e1.x, e1.y, e1.z, e1.w};
        bf16x8 zv;
        #pragma unroll
        for (int q = 0; q < 8; ++q) {
            const float mu = b2f((unsigned short)muv[q]);
            const float lv = b2f((unsigned short)lvv[q]);
            const float z  = fmaf(expf(0.5f * lv), ep[q], mu);
            zv[q] = (short)f2b(z);
            klsum += 0.5f * (expf(lv) + mu * mu - 1.f - lv);
        }
        *(bf16x8*)(Zb + (size_t)m * 1088 + j) = zv;
    }
    __shared__ float wsum[4];
    const int lane = threadIdx.x & 63, wave = threadIdx.x >> 6;
    #pragma unroll
    for (int off = 32; off; off >>= 1) klsum += __shfl_xor(klsum, off);
    if (lane == 0) wsum[wave] = klsum;
    __syncthreads();
    if (threadIdx.x == 0)
        atomicAdd(kl_out, (wsum[0] + wsum[1] + wsum[2] + wsum[3]) * (1.0f / 16384.f));
}

// f32 -> (hi, lo) bf16 split, n % 4 == 0
__global__ __launch_bounds__(256) void conv_split(
    const float* __restrict__ in,
    unsigned short* __restrict__ hi, unsigned short* __restrict__ lo, int n)
{
    const int i = (blockIdx.x * 256 + threadIdx.x) * 4;
    if (i >= n) return;
    const float4 v = *(const float4*)(in + i);
    ushort4 h, l;
    h.x = f2b(v.x); l.x = f2b(v.x - b2f(h.x));
    h.y = f2b(v.y); l.y = f2b(v.y - b2f(h.y));
    h.z = f2b(v.z); l.z = f2b(v.z - b2f(h.z));
    h.w = f2b(v.w); l.w = f2b(v.w - b2f(h.w));
    *(ushort4*)(hi + i) = h;
    *(ushort4*)(lo + i) = l;
}

// W_enc [500][768] -> hi/lo [512][768], rows 500..511 zero
__global__ __launch_bounds__(256) void wenc_split(
    const float* __restrict__ W,
    unsigned short* __restrict__ hi, unsigned short* __restrict__ lo)
{
    const int idx = blockIdx.x * 256 + threadIdx.x;
    if (idx >= 512 * 768) return;
    const int r = idx / 768;
    if (r < 500) {
        const float v = W[idx];
        const unsigned short h = f2b(v);
        hi[idx] = h;
        lo[idx] = f2b(v - b2f(h));
    } else {
        hi[idx] = 0; lo[idx] = 0;
    }
}

// f32 -> bf16 (RNE), n % 4 == 0
__global__ __launch_bounds__(256) void conv_bf16(
    const float* __restrict__ in, unsigned short* __restrict__ out, int n)
{
    const int i = (blockIdx.x * 256 + threadIdx.x) * 4;
    if (i >= n) return;
    const float4 v = *(const float4*)(in + i);
    ushort4 o;
    o.x = f2b(v.x); o.y = f2b(v.y); o.z = f2b(v.z); o.w = f2b(v.w);
    *(ushort4*)(out + i) = o;
}

// Wd [768][1067] f32 -> [768][1088] bf16, zero K-pad
__global__ __launch_bounds__(256) void repack_wd(
    const float* __restrict__ Wd, unsigned short* __restrict__ Wdb)
{
    const int idx = blockIdx.x * 256 + threadIdx.x;
    if (idx >= 768 * 1088) return;
    const int n = idx / 1088;
    const int k = idx - n * 1088;
    Wdb[idx] = (k < 1067) ? f2b(Wd[(size_t)n * 1067 + k]) : 0;
}

extern "C" void kernel_launch(void* const* d_in, const int* in_sizes, int n_in,
                              void* d_out, int out_size, void* d_ws, size_t ws_size,
                              hipStream_t stream) {
    const float* x        = (const float*)d_in[0];
    const int*   known    = (const int*)  d_in[1];
    const int*   labels   = (const int*)  d_in[2];
    const float* eps      = (const float*)d_in[3];
    const float* W_enc    = (const float*)d_in[4];
    const float* b_enc    = (const float*)d_in[5];
    const float* codebook = (const float*)d_in[6];
    const float* W1       = (const float*)d_in[7];
    const float* b1       = (const float*)d_in[8];
    const float* W2       = (const float*)d_in[9];
    const float* b2       = (const float*)d_in[10];
    const float* Wd       = (const float*)d_in[11];
    const float* bd       = (const float*)d_in[12];
    float* out = (float*)d_out;
    char*  ws  = (char*)d_ws;

    unsigned short* xh   = (unsigned short*)(ws + WS_XH);
    unsigned short* xl   = (unsigned short*)(ws + WS_XL);
    unsigned short* Zb   = (unsigned short*)(ws + WS_ZB);
    unsigned short* hb   = (unsigned short*)(ws + WS_HB);
    unsigned short* MLb  = (unsigned short*)(ws + WS_MLB);
    unsigned short* W1b  = (unsigned short*)(ws + WS_W1B);
    unsigned short* W2b  = (unsigned short*)(ws + WS_W2B);
    unsigned short* Wdb  = (unsigned short*)(ws + WS_WDB);
    unsigned short* Weh  = (unsigned short*)(ws + WS_WEH);
    unsigned short* Wel  = (unsigned short*)(ws + WS_WEL);
    unsigned short* cbWh = (unsigned short*)(ws + WS_CBH);
    unsigned short* cbWl = (unsigned short*)(ws + WS_CBL);
    double*         cbWd = (double*)        (ws + WS_CBD);
    float*          lbf  = (float*)         (ws + WS_LBF);
    double*         lbd  = (double*)        (ws + WS_LBD);

    hipMemsetAsync(out + KL_OFF, 0, sizeof(float), stream);

    const dim3 blk(256);
    // conversions / precompute
    conv_split<<<(16384 * 768 / 4 + 255) / 256, blk, 0, stream>>>(x, xh, xl, 16384 * 768);
    conv_bf16<<<(1024 * 768 / 4 + 255) / 256, blk, 0, stream>>>(W1, W1b, 1024 * 768);
    conv_bf16<<<(2048 * 1024 / 4 + 255) / 256, blk, 0, stream>>>(W2, W2b, 2048 * 1024);
    repack_wd<<<(768 * 1088 + 255) / 256, blk, 0, stream>>>(Wd, Wdb);
    wenc_split<<<(512 * 768 + 255) / 256, blk, 0, stream>>>(W_enc, Weh, Wel);
    cbw_kernel<<<128, blk, 0, stream>>>(W_enc, codebook, b_enc,
                                        cbWd, cbWh, cbWl, lbf, lbd);

    // h = relu(x @ W1^T + b1)        [16384,1024] bf16, K=768
    gemm_bf16<true, true><<<dim3(8, B_ROWS / 128), blk, 0, stream>>>(
        xh, W1b, b1, hb, 768, 768, 1024, 768);
    // mu_logvar = h @ W2^T + b2      [16384,2048] bf16, K=1024
    gemm_bf16<false, true><<<dim3(16, B_ROWS / 128), blk, 0, stream>>>(
        hb, W2b, b2, MLb, 1024, 1024, 2048, 1024);
    // z_e_x = x @ W_enc^T + b_enc    [16384,500] f32, split-bf16, K=768
    gemm_bf16x3<true><<<dim3(4, B_ROWS / 128), blk, 0, stream>>>(
        xh, xl, Weh, Wel, b_enc, out + ZE_OFF, 768, 768, 500, 500, 768);
    // logits = x @ cbW^T + lb        [16384,43] f32, split-bf16, K=768
    gemm_bf16x3<true><<<dim3(1, B_ROWS / 128), blk, 0, stream>>>(
        xh, xl, cbWh, cbWl, lbf, out + LOG_OFF, 768, 768, 43, 43, 768);
    // head: argmax(+fp64 repair)/softmax/y/z_q_x
    head_kernel<<<B_ROWS / 4, blk, 0, stream>>>(
        out + LOG_OFF, codebook, known, labels, x, cbWd, lbd,
        out + ZQ_OFF, Zb);
    // sampled_z + kl
    vae_sample<<<2048, blk, 0, stream>>>(MLb, eps, Zb, out + KL_OFF);
    // x_tilde = [sampled_z | y] @ Wd^T + bd   [16384,768] f32, K=1088
    gemm_bf16<false, false><<<dim3(6, B_ROWS / 128), blk, 0, stream>>>(
        Zb, Wdb, bd, out + X_TILDE_OFF, 1088, 1088, 768, 1088);
}

// Round 4
// 593.821 us; speedup vs baseline: 3.4563x; 1.0817x over previous
//
#include <hip/hip_runtime.h>
#include <hip/hip_bf16.h>
#include <math.h>

// ---------------------------------------------------------------------------
// VQVAE forward.
//  - 2-phase double-buffered counted-vmcnt bf16 MFMA GEMMs (T3-min + T4)
//  - vae_sample fused into the mu_logvar GEMM epilogue via W2 row permutation
//  - z_e plain bf16; logits bf16x3 (x @ cbW^T) with fp64 near-tie repair
// Outputs: x_tilde[16384,768], z_e_x[16384,500], z_q_x[16384,500],
// logits[16384,43], kl_div[1]
// ---------------------------------------------------------------------------

#define B_ROWS 16384

typedef __attribute__((ext_vector_type(8))) short bf16x8;
typedef __attribute__((ext_vector_type(4))) float f32x4;

constexpr size_t X_TILDE_OFF = 0;
constexpr size_t ZE_OFF      = 12582912;
constexpr size_t ZQ_OFF      = 20774912;
constexpr size_t LOG_OFF     = 28966912;
constexpr size_t KL_OFF      = 29671424;

// ws byte offsets (~128.5 MB total)
constexpr size_t WS_XH  = 0;            // [16384][768]  bf16 hi(x)
constexpr size_t WS_XL  = 25165824;     // [16384][768]  bf16 lo(x)
constexpr size_t WS_ZB  = 50331648;     // [16384][1088] bf16 concat [z|y]
constexpr size_t WS_HB  = 85983232;     // [16384][1024] bf16 h
constexpr size_t WS_W1B = 119537664;    // [1024][768]  bf16
constexpr size_t WS_W2P = 121110528;    // [2048][1024] bf16, row-permuted
constexpr size_t WS_WDB = 125304832;    // [768][1088]  bf16
constexpr size_t WS_WEH = 126976000;    // [512][768]   bf16 hi(W_enc), rows 500+ zero
constexpr size_t WS_CBH = 127762432;    // [128][768]   bf16 hi(cbW), rows 43+ zero
constexpr size_t WS_CBL = 127959040;    // [128][768]   bf16 lo(cbW)
constexpr size_t WS_CBD = 128155648;    // [43][768]    f64 cbW (repair)
constexpr size_t WS_LBF = 128419840;    // [128]        f32 logits bias (padded)
constexpr size_t WS_LBD = 128420352;    // [43]         f64 logits bias

__device__ __forceinline__ unsigned short f2b(float f) {
    unsigned u = __builtin_bit_cast(unsigned, f);
    return (unsigned short)((u + 0x7FFFu + ((u >> 16) & 1u)) >> 16);
}
__device__ __forceinline__ float b2f(unsigned short u) {
    return __uint_as_float(((unsigned)u) << 16);
}

__device__ __forceinline__ void stage16(const void* g, void* l) {
    __builtin_amdgcn_global_load_lds(
        (const __attribute__((address_space(1))) void*)g,
        (__attribute__((address_space(3))) void*)l, 16, 0, 0);
}

// ---------------------------------------------------------------------------
// 2-phase double-buffered K-loop, 128x128 tile, BK=32, 4 waves.
// Counted vmcnt(4): the prefetch issued at iter t is awaited at iter t+1,
// hiding its latency under iter t's MFMA. vmcnt never drains to 0 mid-loop.
// ---------------------------------------------------------------------------
__device__ __forceinline__ void gemm_loop(
    const unsigned short* __restrict__ A,
    const unsigned short* __restrict__ Bw,
    int lda, int ldb, int K, int row0, int col0,
    short* As, short* Bs, f32x4 acc[4][4])
{
    const int t = threadIdx.x;
    const int w = t >> 6, l = t & 63;
    const int wr = (w >> 1) * 64, wc = (w & 1) * 64;
    const unsigned short* a0 = A  + (size_t)(row0 + (t >> 2)) * lda + ((t & 3) << 3);
    const unsigned short* b0 = Bw + (size_t)(col0 + (t >> 2)) * ldb + ((t & 3) << 3);
    const size_t aStep = (size_t)64 * lda, bStep = (size_t)64 * ldb;
    const int fr = l & 15, fk = (l >> 4) << 3;
    const int s0 = t * 8, s1 = (256 + t) * 8;

    stage16(a0, As + s0); stage16(a0 + aStep, As + s1);
    stage16(b0, Bs + s0); stage16(b0 + bStep, Bs + s1);

    int cur = 0;
    for (int k0 = 0; k0 < K; k0 += 32) {
        const int nb = (cur ^ 1) * 4096;
        if (k0 + 32 < K) {
            stage16(a0 + k0 + 32,         As + nb + s0);
            stage16(a0 + aStep + k0 + 32, As + nb + s1);
            stage16(b0 + k0 + 32,         Bs + nb + s0);
            stage16(b0 + bStep + k0 + 32, Bs + nb + s1);
            asm volatile("s_waitcnt vmcnt(4)" ::: "memory");
        } else {
            asm volatile("s_waitcnt vmcnt(0)" ::: "memory");
        }
        __builtin_amdgcn_s_barrier();   // all waves' cur-buffer loads done
        const short* cA = As + cur * 4096;
        const short* cB = Bs + cur * 4096;
        bf16x8 am[4], bn[4];
        #pragma unroll
        for (int i = 0; i < 4; ++i)
            am[i] = *(const bf16x8*)&cA[(wr + i * 16 + fr) * 32 + fk];
        #pragma unroll
        for (int j = 0; j < 4; ++j)
            bn[j] = *(const bf16x8*)&cB[(wc + j * 16 + fr) * 32 + fk];
        #pragma unroll
        for (int i = 0; i < 4; ++i)
            #pragma unroll
            for (int j = 0; j < 4; ++j)
                acc[i][j] = __builtin_amdgcn_mfma_f32_16x16x32_bf16(
                    am[i], bn[j], acc[i][j], 0, 0, 0);
        __builtin_amdgcn_s_barrier();   // reads done before next-iter staging
        cur ^= 1;
    }
}

enum { EPI_H = 0, EPI_XT = 1, EPI_ZE = 2, EPI_ML = 3 };

// C/D layout: col = lane&15, row = (lane>>4)*4 + reg   [m89/m91]
template<int EPI>
__global__ __launch_bounds__(256) void gemm2(
    const unsigned short* __restrict__ A,
    const unsigned short* __restrict__ Bw,
    const float* __restrict__ bias,   // EPI_ML: raw b2[2048]
    void* __restrict__ C,             // H: ushort; XT/ZE: float; ML: Zb ushort
    const float* __restrict__ eps,    // ML only
    float* __restrict__ kl,           // ML only
    int lda, int ldb, int ldc, int K)
{
    __shared__ short As[2 * 4096];
    __shared__ short Bs[2 * 4096];
    __shared__ float wsum[4];
    f32x4 acc[4][4] = {};
    const int row0 = blockIdx.y * 128, col0 = blockIdx.x * 128;
    gemm_loop(A, Bw, lda, ldb, K, row0, col0, As, Bs, acc);

    const int t = threadIdx.x, w = t >> 6, l = t & 63;
    const int wr = (w >> 1) * 64, wc = (w & 1) * 64;
    const int fr = l & 15, fq = (l >> 4) << 2;

    if constexpr (EPI == EPI_ML) {
        // fragment pair (2jj, 2jj+1) = (mu, logvar) of vae dim d (W2 row-perm)
        float klsum = 0.f;
        #pragma unroll
        for (int i = 0; i < 4; ++i) {
            #pragma unroll
            for (int jj = 0; jj < 2; ++jj) {
                const int d = ((col0 + wc) >> 1) + jj * 16 + fr;
                const float bmu = bias[d], blv = bias[1024 + d];
                #pragma unroll
                for (int q = 0; q < 4; ++q) {
                    const int r = row0 + wr + i * 16 + fq + q;
                    const float mu = acc[i][2 * jj][q] + bmu;
                    const float lv = acc[i][2 * jj + 1][q] + blv;
                    const float e  = eps[(size_t)r * 1024 + d];
                    const float z  = fmaf(expf(0.5f * lv), e, mu);
                    ((unsigned short*)C)[(size_t)r * 1088 + d] = f2b(z);
                    klsum += 0.5f * (expf(lv) + mu * mu - 1.f - lv);
                }
            }
        }
        #pragma unroll
        for (int off = 32; off; off >>= 1) klsum += __shfl_xor(klsum, off);
        if (l == 0) wsum[w] = klsum;
        __syncthreads();
        if (t == 0)
            atomicAdd(kl, (wsum[0] + wsum[1] + wsum[2] + wsum[3]) * (1.0f / 16384.f));
    } else {
        #pragma unroll
        for (int i = 0; i < 4; ++i) {
            #pragma unroll
            for (int j = 0; j < 4; ++j) {
                const int c = col0 + wc + j * 16 + fr;
                if (EPI == EPI_ZE && c >= 500) continue;
                const int r0 = row0 + wr + i * 16 + fq;
                const float bv = bias[c];
                #pragma unroll
                for (int q = 0; q < 4; ++q) {
                    float v = acc[i][j][q] + bv;
                    if (EPI == EPI_H) v = fmaxf(v, 0.f);
                    if (EPI == EPI_H)
                        ((unsigned short*)C)[(size_t)(r0 + q) * ldc + c] = f2b(v);
                    else
                        ((float*)C)[(size_t)(r0 + q) * ldc + c] = v;
                }
            }
        }
    }
}

// ---------------------------------------------------------------------------
// logits = x @ cbW^T + lb, split-bf16 (hi*hi + lo*hi + hi*lo), 2-phase.
// N=128 (43 + zero pad), lda=ldb=768, grid (1, 128).
// ---------------------------------------------------------------------------
__global__ __launch_bounds__(256) void gemm_x3_logits(
    const unsigned short* __restrict__ Ah,
    const unsigned short* __restrict__ Al,
    const unsigned short* __restrict__ Bh,
    const unsigned short* __restrict__ Bl,
    const float* __restrict__ bias,
    float* __restrict__ C, int K)
{
    __shared__ short sAh[2 * 4096], sAl[2 * 4096];
    __shared__ short sBh[2 * 4096], sBl[2 * 4096];
    const int t = threadIdx.x, w = t >> 6, l = t & 63;
    const int row0 = blockIdx.y * 128;
    const int wr = (w >> 1) * 64, wc = (w & 1) * 64;
    const size_t aoff = (size_t)(row0 + (t >> 2)) * 768 + ((t & 3) << 3);
    const size_t boff = (size_t)(t >> 2) * 768 + ((t & 3) << 3);
    const size_t step = (size_t)64 * 768;
    const int s0 = t * 8, s1 = (256 + t) * 8;
    const int fr = l & 15, fk = (l >> 4) << 3;
    f32x4 acc[4][4] = {};

    #define STAGE_ALL(buf, k)                                                  \
        stage16(Ah + aoff + (k),        sAh + (buf) * 4096 + s0);              \
        stage16(Ah + aoff + step + (k), sAh + (buf) * 4096 + s1);              \
        stage16(Al + aoff + (k),        sAl + (buf) * 4096 + s0);              \
        stage16(Al + aoff + step + (k), sAl + (buf) * 4096 + s1);              \
        stage16(Bh + boff + (k),        sBh + (buf) * 4096 + s0);              \
        stage16(Bh + boff + step + (k), sBh + (buf) * 4096 + s1);              \
        stage16(Bl + boff + (k),        sBl + (buf) * 4096 + s0);              \
        stage16(Bl + boff + step + (k), sBl + (buf) * 4096 + s1);

    STAGE_ALL(0, 0)
    int cur = 0;
    for (int k0 = 0; k0 < K; k0 += 32) {
        if (k0 + 32 < K) {
            STAGE_ALL(cur ^ 1, k0 + 32)
            asm volatile("s_waitcnt vmcnt(8)" ::: "memory");
        } else {
            asm volatile("s_waitcnt vmcnt(0)" ::: "memory");
        }
        __builtin_amdgcn_s_barrier();
        const short* cAh = sAh + cur * 4096;  const short* cAl = sAl + cur * 4096;
        const short* cBh = sBh + cur * 4096;  const short* cBl = sBl + cur * 4096;
        bf16x8 ah[4], al[4], bh[4], bl[4];
        #pragma unroll
        for (int i = 0; i < 4; ++i) {
            ah[i] = *(const bf16x8*)&cAh[(wr + i * 16 + fr) * 32 + fk];
            al[i] = *(const bf16x8*)&cAl[(wr + i * 16 + fr) * 32 + fk];
        }
        #pragma unroll
        for (int j = 0; j < 4; ++j) {
            bh[j] = *(const bf16x8*)&cBh[(wc + j * 16 + fr) * 32 + fk];
            bl[j] = *(const bf16x8*)&cBl[(wc + j * 16 + fr) * 32 + fk];
        }
        #pragma unroll
        for (int i = 0; i < 4; ++i)
            #pragma unroll
            for (int j = 0; j < 4; ++j) {
                acc[i][j] = __builtin_amdgcn_mfma_f32_16x16x32_bf16(
                    ah[i], bh[j], acc[i][j], 0, 0, 0);
                acc[i][j] = __builtin_amdgcn_mfma_f32_16x16x32_bf16(
                    al[i], bh[j], acc[i][j], 0, 0, 0);
                acc[i][j] = __builtin_amdgcn_mfma_f32_16x16x32_bf16(
                    ah[i], bl[j], acc[i][j], 0, 0, 0);
            }
        __builtin_amdgcn_s_barrier();
        cur ^= 1;
    }
    #undef STAGE_ALL

    const int fq = (l >> 4) << 2;
    #pragma unroll
    for (int i = 0; i < 4; ++i)
        #pragma unroll
        for (int j = 0; j < 4; ++j) {
            const int c = wc + j * 16 + fr;
            if (c < 43) {
                const int r0 = row0 + wr + i * 16 + fq;
                const float bv = bias[c];
                #pragma unroll
                for (int q = 0; q < 4; ++q)
                    C[(size_t)(r0 + q) * 43 + c] = acc[i][j][q] + bv;
            }
        }
}

// ---------------------------------------------------------------------------
// cbW = codebook @ W_enc [43][768] fp64; bf16 hi/lo (rows padded to 128);
// lb = codebook @ b_enc.
// ---------------------------------------------------------------------------
__global__ __launch_bounds__(256) void cbw_kernel(
    const float* __restrict__ W_enc, const float* __restrict__ cb,
    const float* __restrict__ b_enc,
    double* __restrict__ cbWd, unsigned short* __restrict__ cbWh,
    unsigned short* __restrict__ cbWl, float* __restrict__ lbf,
    double* __restrict__ lbd)
{
    const int j = blockIdx.x;   // 0..127
    const int t = threadIdx.x;
    if (j >= 43) {
        for (int d = t; d < 768; d += 256) {
            cbWh[(size_t)j * 768 + d] = 0;
            cbWl[(size_t)j * 768 + d] = 0;
        }
        if (t == 0) lbf[j] = 0.f;
        return;
    }
    double acc[3] = {0.0, 0.0, 0.0};
    for (int k = 0; k < 500; ++k) {
        const double c = (double)cb[(size_t)j * 500 + k];
        acc[0] = fma(c, (double)W_enc[(size_t)k * 768 + t],       acc[0]);
        acc[1] = fma(c, (double)W_enc[(size_t)k * 768 + t + 256], acc[1]);
        acc[2] = fma(c, (double)W_enc[(size_t)k * 768 + t + 512], acc[2]);
    }
    #pragma unroll
    for (int q = 0; q < 3; ++q) {
        const int d = t + q * 256;
        const double v = acc[q];
        cbWd[(size_t)j * 768 + d] = v;
        const float f = (float)v;
        const unsigned short h = f2b(f);
        cbWh[(size_t)j * 768 + d] = h;
        cbWl[(size_t)j * 768 + d] = f2b(f - b2f(h));
    }
    if (t == 0) {
        double s = 0.0;
        for (int k = 0; k < 500; ++k)
            s = fma((double)cb[(size_t)j * 500 + k], (double)b_enc[k], s);
        lbd[j] = s;
        lbf[j] = (float)s;
    }
}

// ---------------------------------------------------------------------------
// Head: argmax (fp64 repair for near-ties), softmax, y (bf16) into Zb cols
// 1024..1087, z_q_x = codebook[argmax].
// ---------------------------------------------------------------------------
__global__ __launch_bounds__(256) void head_kernel(
    const float* __restrict__ logits, const float* __restrict__ codebook,
    const int* __restrict__ known_mask, const int* __restrict__ labels,
    const float* __restrict__ x, const double* __restrict__ cbWd,
    const double* __restrict__ lbd,
    float* __restrict__ zq_out, unsigned short* __restrict__ Zb)
{
    const int wave = threadIdx.x >> 6;
    const int lane = threadIdx.x & 63;
    const int row  = blockIdx.x * 4 + wave;

    const float* lrow = logits + (size_t)row * 43;
    const float v = (lane < 43) ? lrow[lane] : -INFINITY;

    float bvv = v; int bi = lane;
    #pragma unroll
    for (int off = 32; off; off >>= 1) {
        const float ov = __shfl_xor(bvv, off);
        const int   oi = __shfl_xor(bi, off);
        if (ov > bvv || (ov == bvv && oi < bi)) { bvv = ov; bi = oi; }
    }
    float v2 = (lane == bi) ? -INFINITY : v;
    #pragma unroll
    for (int off = 32; off; off >>= 1) v2 = fmaxf(v2, __shfl_xor(v2, off));

    int idx = bi;
    if (bvv - v2 < 1e-3f) {   // near-tie: fp64 recompute (wave-uniform)
        double dv = -1.0e300;
        if (lane < 43) {
            double s = lbd[lane];
            const float* xr = x + (size_t)row * 768;
            const double* wrow = cbWd + (size_t)lane * 768;
            for (int d = 0; d < 768; ++d)
                s = fma((double)xr[d], wrow[d], s);
            dv = s;
        }
        double bdv = dv; int bj = lane;
        #pragma unroll
        for (int off = 32; off; off >>= 1) {
            const double ov = __shfl_xor(bdv, off);
            const int    oi = __shfl_xor(bj, off);
            if (ov > bdv || (ov == bdv && oi < bj)) { bdv = ov; bj = oi; }
        }
        idx = bj;
    }

    float e = (lane < 43) ? expf(v - bvv) : 0.f;
    float s = e;
    #pragma unroll
    for (int off = 32; off; off >>= 1) s += __shfl_xor(s, off);

    const int km  = known_mask[row];
    const int lab = labels[row];
    float y;
    if (lane < 43) y = km ? ((lane == lab) ? 1.f : 0.f) : (e / s);
    else           y = 0.f;   // zeros K-pad cols 1067..1087
    Zb[(size_t)row * 1088 + 1024 + lane] = f2b(y);

    const float* crow = codebook + (size_t)idx * 500;
    float* zrow = zq_out + (size_t)row * 500;
    for (int c = lane; c < 500; c += 64) zrow[c] = crow[c];
}

// f32 -> (hi, lo) bf16 split, n % 4 == 0
__global__ __launch_bounds__(256) void conv_split(
    const float* __restrict__ in,
    unsigned short* __restrict__ hi, unsigned short* __restrict__ lo, int n)
{
    const int i = (blockIdx.x * 256 + threadIdx.x) * 4;
    if (i >= n) return;
    const float4 v = *(const float4*)(in + i);
    ushort4 h, l;
    h.x = f2b(v.x); l.x = f2b(v.x - b2f(h.x));
    h.y = f2b(v.y); l.y = f2b(v.y - b2f(h.y));
    h.z = f2b(v.z); l.z = f2b(v.z - b2f(h.z));
    h.w = f2b(v.w); l.w = f2b(v.w - b2f(h.w));
    *(ushort4*)(hi + i) = h;
    *(ushort4*)(lo + i) = l;
}

// f32 -> bf16 (RNE), n % 4 == 0
__global__ __launch_bounds__(256) void conv_bf16(
    const float* __restrict__ in, unsigned short* __restrict__ out, int n)
{
    const int i = (blockIdx.x * 256 + threadIdx.x) * 4;
    if (i >= n) return;
    const float4 v = *(const float4*)(in + i);
    ushort4 o;
    o.x = f2b(v.x); o.y = f2b(v.y); o.z = f2b(v.z); o.w = f2b(v.w);
    *(ushort4*)(out + i) = o;
}

// W_enc [500][768] -> hi [512][768], rows 500..511 zero
__global__ __launch_bounds__(256) void wenc_hi(
    const float* __restrict__ W, unsigned short* __restrict__ hi)
{
    const int idx = blockIdx.x * 256 + threadIdx.x;
    if (idx >= 512 * 768) return;
    const int r = idx / 768;
    hi[idx] = (r < 500) ? f2b(W[idx]) : 0;
}

// W2 [2048][1024] -> W2p [2048][1024] bf16, rows permuted so that output
// col 32g+s (s<16) = mu_{16g+s} and col 32g+16+s = logvar_{16g+s}.
__global__ __launch_bounds__(256) void repack_w2p(
    const float* __restrict__ W2, unsigned short* __restrict__ W2p)
{
    const int idx = blockIdx.x * 256 + threadIdx.x;
    if (idx >= 2048 * 1024) return;
    const int c = idx >> 10;
    const int k = idx & 1023;
    const int s = c & 31, g = c >> 5;
    const int src = ((s < 16) ? 0 : 1024) + g * 16 + (s & 15);
    W2p[idx] = f2b(W2[(size_t)src * 1024 + k]);
}

// Wd [768][1067] f32 -> [768][1088] bf16, zero K-pad
__global__ __launch_bounds__(256) void repack_wd(
    const float* __restrict__ Wd, unsigned short* __restrict__ Wdb)
{
    const int idx = blockIdx.x * 256 + threadIdx.x;
    if (idx >= 768 * 1088) return;
    const int n = idx / 1088;
    const int k = idx - n * 1088;
    Wdb[idx] = (k < 1067) ? f2b(Wd[(size_t)n * 1067 + k]) : 0;
}

extern "C" void kernel_launch(void* const* d_in, const int* in_sizes, int n_in,
                              void* d_out, int out_size, void* d_ws, size_t ws_size,
                              hipStream_t stream) {
    const float* x        = (const float*)d_in[0];
    const int*   known    = (const int*)  d_in[1];
    const int*   labels   = (const int*)  d_in[2];
    const float* eps      = (const float*)d_in[3];
    const float* W_enc    = (const float*)d_in[4];
    const float* b_enc    = (const float*)d_in[5];
    const float* codebook = (const float*)d_in[6];
    const float* W1       = (const float*)d_in[7];
    const float* b1       = (const float*)d_in[8];
    const float* W2       = (const float*)d_in[9];
    const float* b2       = (const float*)d_in[10];
    const float* Wd       = (const float*)d_in[11];
    const float* bd       = (const float*)d_in[12];
    float* out = (float*)d_out;
    char*  ws  = (char*)d_ws;

    unsigned short* xh   = (unsigned short*)(ws + WS_XH);
    unsigned short* xl   = (unsigned short*)(ws + WS_XL);
    unsigned short* Zb   = (unsigned short*)(ws + WS_ZB);
    unsigned short* hb   = (unsigned short*)(ws + WS_HB);
    unsigned short* W1b  = (unsigned short*)(ws + WS_W1B);
    unsigned short* W2p  = (unsigned short*)(ws + WS_W2P);
    unsigned short* Wdb  = (unsigned short*)(ws + WS_WDB);
    unsigned short* Weh  = (unsigned short*)(ws + WS_WEH);
    unsigned short* cbWh = (unsigned short*)(ws + WS_CBH);
    unsigned short* cbWl = (unsigned short*)(ws + WS_CBL);
    double*         cbWd = (double*)        (ws + WS_CBD);
    float*          lbf  = (float*)         (ws + WS_LBF);
    double*         lbd  = (double*)        (ws + WS_LBD);

    hipMemsetAsync(out + KL_OFF, 0, sizeof(float), stream);

    const dim3 blk(256);
    conv_split<<<(16384 * 768 / 4 + 255) / 256, blk, 0, stream>>>(x, xh, xl, 16384 * 768);
    conv_bf16<<<(1024 * 768 / 4 + 255) / 256, blk, 0, stream>>>(W1, W1b, 1024 * 768);
    repack_w2p<<<(2048 * 1024 + 255) / 256, blk, 0, stream>>>(W2, W2p);
    repack_wd<<<(768 * 1088 + 255) / 256, blk, 0, stream>>>(Wd, Wdb);
    wenc_hi<<<(512 * 768 + 255) / 256, blk, 0, stream>>>(W_enc, Weh);
    cbw_kernel<<<128, blk, 0, stream>>>(W_enc, codebook, b_enc,
                                        cbWd, cbWh, cbWl, lbf, lbd);

    // h = relu(x @ W1^T + b1)   [16384,1024] bf16
    gemm2<EPI_H><<<dim3(8, 128), blk, 0, stream>>>(
        xh, W1b, b1, hb, nullptr, nullptr, 768, 768, 1024, 768);
    // mu_logvar GEMM fused with sampling + KL -> Zb cols 0..1023
    gemm2<EPI_ML><<<dim3(16, 128), blk, 0, stream>>>(
        hb, W2p, b2, Zb, eps, out + KL_OFF, 1024, 1024, 0, 1024);
    // z_e_x = x @ W_enc^T + b_enc   [16384,500] f32, plain bf16
    gemm2<EPI_ZE><<<dim3(4, 128), blk, 0, stream>>>(
        xh, Weh, b_enc, out + ZE_OFF, nullptr, nullptr, 768, 768, 500, 768);
    // logits = x @ cbW^T + lb   [16384,43] f32, split-bf16
    gemm_x3_logits<<<dim3(1, 128), blk, 0, stream>>>(
        xh, xl, cbWh, cbWl, lbf, out + LOG_OFF, 768);
    // head: argmax(+fp64 repair)/softmax/y/z_q_x
    head_kernel<<<B_ROWS / 4, blk, 0, stream>>>(
        out + LOG_OFF, codebook, known, labels, x, cbWd, lbd,
        out + ZQ_OFF, Zb);
    // x_tilde = [sampled_z | y] @ Wd^T + bd   [16384,768] f32
    gemm2<EPI_XT><<<dim3(6, 128), blk, 0, stream>>>(
        Zb, Wdb, bd, out + X_TILDE_OFF, nullptr, nullptr, 1088, 1088, 768, 1088);
}

// Round 6
// 560.956 us; speedup vs baseline: 3.6587x; 1.0586x over previous
//
#include <hip/hip_runtime.h>
#include <hip/hip_bf16.h>
#include <math.h>

// ---------------------------------------------------------------------------
// VQVAE forward.
//  - 256x256-tile 8-wave 4-phase/K-tile counted-vmcnt bf16 MFMA GEMM
//    (T1 xcd-swizzle + T2 lds-swizzle + T3/T4 phased counted vmcnt + T5 setprio)
//  - vae_sample fused into the mu_logvar GEMM epilogue via W2 row permutation
//  - z_e plain bf16; logits bf16x3 (x @ cbW^T) with fp64 near-tie repair
// Outputs: x_tilde[16384,768], z_e_x[16384,500], z_q_x[16384,500],
// logits[16384,43], kl_div[1]
// ---------------------------------------------------------------------------

#define B_ROWS 16384

typedef __attribute__((ext_vector_type(8))) short bf16x8;
typedef __attribute__((ext_vector_type(4))) float f32x4;

constexpr size_t X_TILDE_OFF = 0;
constexpr size_t ZE_OFF      = 12582912;
constexpr size_t ZQ_OFF      = 20774912;
constexpr size_t LOG_OFF     = 28966912;
constexpr size_t KL_OFF      = 29671424;

// ws byte offsets (~128.5 MB total)
constexpr size_t WS_XH  = 0;            // [16384][768]  bf16 hi(x)
constexpr size_t WS_XL  = 25165824;     // [16384][768]  bf16 lo(x)
constexpr size_t WS_ZB  = 50331648;     // [16384][1088] bf16 concat [z|y]
constexpr size_t WS_HB  = 85983232;     // [16384][1024] bf16 h
constexpr size_t WS_W1B = 119537664;    // [1024][768]  bf16
constexpr size_t WS_W2P = 121110528;    // [2048][1024] bf16, row-permuted
constexpr size_t WS_WDB = 125304832;    // [768][1088]  bf16
constexpr size_t WS_WEH = 126976000;    // [512][768]   bf16 hi(W_enc), rows 500+ zero
constexpr size_t WS_CBH = 127762432;    // [128][768]   bf16 hi(cbW), rows 43+ zero
constexpr size_t WS_CBL = 127959040;    // [128][768]   bf16 lo(cbW)
constexpr size_t WS_CBD = 128155648;    // [43][768]    f64 cbW (repair)
constexpr size_t WS_LBF = 128419840;    // [128]        f32 logits bias (padded)
constexpr size_t WS_LBD = 128420352;    // [43]         f64 logits bias

__device__ __forceinline__ unsigned short f2b(float f) {
    unsigned u = __builtin_bit_cast(unsigned, f);
    return (unsigned short)((u + 0x7FFFu + ((u >> 16) & 1u)) >> 16);
}
__device__ __forceinline__ float b2f(unsigned short u) {
    return __uint_as_float(((unsigned)u) << 16);
}

__device__ __forceinline__ void stage16(const void* g, void* l) {
    __builtin_amdgcn_global_load_lds(
        (const __attribute__((address_space(1))) void*)g,
        (__attribute__((address_space(3))) void*)l, 16, 0, 0);
}

// LDS unit layout: [256 rows][32 cols] bf16, swizzled: element col c of row r
// stored at col c ^ (((r>>1)&3)<<3). Applied on the gload_lds GLOBAL SOURCE
// (LDS dest stays linear) and again on the ds_read address (rule #21).
__device__ __forceinline__ int swz(int row, int cb) {
    return cb ^ (((row >> 1) & 3) << 3);
}

// stage one 16KB unit (256 rows x 32 cols) with 512 threads x 2 loads x 16B
__device__ __forceinline__ void stage_unit(const unsigned short* __restrict__ src,
                                           int ld, int r0, int k0,
                                           short* unit, int t) {
    #pragma unroll
    for (int j = 0; j < 2; ++j) {
        const int idx = j * 512 + t;       // 16B chunk index
        const int row = idx >> 2;          // 4 chunks per 64B row
        const int cb  = (idx & 3) << 3;    // linear col block 0,8,16,24
        stage16(src + (size_t)(r0 + row) * ld + k0 + swz(row, cb),
                unit + idx * 8);
    }
}

__device__ __forceinline__ bf16x8 lds_frag(const short* unit, int row, int fk) {
    return *(const bf16x8*)(unit + row * 32 + swz(row, fk));
}

#define MFMA16(ACCBASE, AF, BF)                                               \
    _Pragma("unroll")                                                         \
    for (int m = 0; m < 4; ++m)                                               \
        _Pragma("unroll")                                                     \
        for (int n = 0; n < 4; ++n)                                           \
            acc[ACCBASE + m][n] = __builtin_amdgcn_mfma_f32_16x16x32_bf16(    \
                AF[m], BF[n], acc[ACCBASE + m][n], 0, 0, 0);

enum { EPI_H = 0, EPI_XT = 1, EPI_ZE = 2, EPI_ML = 3 };

// ---------------------------------------------------------------------------
// 256x256 tile, BK=64, 8 waves (2M x 4N), per-wave 128x64 output (8x4 frags).
// 4 phases per K-tile; counted vmcnt(4) at phase ends 2 and 4 only.
// ---------------------------------------------------------------------------
template<int EPI>
__global__ __launch_bounds__(512, 2) void gemm8(
    const unsigned short* __restrict__ A,
    const unsigned short* __restrict__ Bw,
    const float* __restrict__ bias,   // EPI_ML: raw b2[2048]
    void* __restrict__ Cv,
    const float* __restrict__ eps,    // ML only
    float* __restrict__ kl,           // ML only
    int lda, int ldb, int ldc, int K, int gx)
{
    __shared__ short As[2][2][8192];   // [dbuf][kslice][256*32]
    __shared__ short Bs[2][2][8192];
    __shared__ float wsum[8];

    // bijective XCD swizzle (grid % 8 == 0 for all launches)
    int wg = blockIdx.x;
    wg = (wg & 7) * ((int)gridDim.x >> 3) + (wg >> 3);
    const int row0 = (wg / gx) * 256;
    const int col0 = (wg % gx) * 256;

    const int t = threadIdx.x;
    const int w = t >> 6, l = t & 63;
    const int arow = (w >> 2) * 128;   // wave M base in tile
    const int bcol = (w & 3) * 64;     // wave N base in tile
    const int fr = l & 15, fk = (l >> 4) << 3, fq = (l >> 4) << 2;

    f32x4 acc[8][4] = {};
    bf16x8 af[4], bf[4];

    // prologue: stage tile 0 (A_k0, B_k0, A_k1, B_k1)
    stage_unit(A, lda, row0, 0,  As[0][0], t);
    stage_unit(Bw, ldb, col0, 0, Bs[0][0], t);
    stage_unit(A, lda, row0, 32, As[0][1], t);
    stage_unit(Bw, ldb, col0, 32, Bs[0][1], t);
    asm volatile("s_waitcnt vmcnt(4)" ::: "memory");   // A_k0,B_k0 landed
    asm volatile("s_barrier" ::: "memory");

    const int NT = K >> 6;
    for (int tt = 0; tt < NT; ++tt) {
        const int cur = tt & 1, nxt = cur ^ 1;
        const int kn = (tt + 1) << 6;
        const bool pf = (tt + 1) < NT;

        // ---- P1: kslice0, m0-3
        #pragma unroll
        for (int m = 0; m < 4; ++m)
            af[m] = lds_frag(As[cur][0], arow + m * 16 + fr, fk);
        #pragma unroll
        for (int n = 0; n < 4; ++n)
            bf[n] = lds_frag(Bs[cur][0], bcol + n * 16 + fr, fk);
        if (pf) stage_unit(A, lda, row0, kn, As[nxt][0], t);
        asm volatile("s_barrier" ::: "memory");
        __builtin_amdgcn_s_setprio(1);
        MFMA16(0, af, bf)
        __builtin_amdgcn_s_setprio(0);
        asm volatile("s_barrier" ::: "memory");

        // ---- P2: kslice0, m4-7 (B frags reused in regs)
        #pragma unroll
        for (int m = 0; m < 4; ++m)
            af[m] = lds_frag(As[cur][0], arow + 64 + m * 16 + fr, fk);
        if (pf) stage_unit(Bw, ldb, col0, kn, Bs[nxt][0], t);
        asm volatile("s_barrier" ::: "memory");
        __builtin_amdgcn_s_setprio(1);
        MFMA16(4, af, bf)
        __builtin_amdgcn_s_setprio(0);
        if (pf) asm volatile("s_waitcnt vmcnt(4)" ::: "memory");  // drain A_k1,B_k1(t)
        else    asm volatile("s_waitcnt vmcnt(0)" ::: "memory");
        asm volatile("s_barrier" ::: "memory");

        // ---- P3: kslice1, m0-3
        #pragma unroll
        for (int m = 0; m < 4; ++m)
            af[m] = lds_frag(As[cur][1], arow + m * 16 + fr, fk);
        #pragma unroll
        for (int n = 0; n < 4; ++n)
            bf[n] = lds_frag(Bs[cur][1], bcol + n * 16 + fr, fk);
        if (pf) stage_unit(A, lda, row0, kn + 32, As[nxt][1], t);
        asm volatile("s_barrier" ::: "memory");
        __builtin_amdgcn_s_setprio(1);
        MFMA16(0, af, bf)
        __builtin_amdgcn_s_setprio(0);
        asm volatile("s_barrier" ::: "memory");

        // ---- P4: kslice1, m4-7
        #pragma unroll
        for (int m = 0; m < 4; ++m)
            af[m] = lds_frag(As[cur][1], arow + 64 + m * 16 + fr, fk);
        if (pf) stage_unit(Bw, ldb, col0, kn + 32, Bs[nxt][1], t);
        asm volatile("s_barrier" ::: "memory");
        __builtin_amdgcn_s_setprio(1);
        MFMA16(4, af, bf)
        __builtin_amdgcn_s_setprio(0);
        if (pf) asm volatile("s_waitcnt vmcnt(4)" ::: "memory");  // drain A_k0,B_k0(t+1)
        else    asm volatile("s_waitcnt vmcnt(0)" ::: "memory");
        asm volatile("s_barrier" ::: "memory");
    }

    // ---- epilogue.  C/D layout: col = lane&15, row = (lane>>4)*4 + reg
    if constexpr (EPI == EPI_ML) {
        float klsum = 0.f;
        const int dbase = (col0 + bcol) >> 1;
        #pragma unroll
        for (int m = 0; m < 8; ++m) {
            #pragma unroll
            for (int pr = 0; pr < 2; ++pr) {
                const int d = dbase + pr * 16 + fr;
                const float bmu = bias[d], blv = bias[1024 + d];
                #pragma unroll
                for (int q = 0; q < 4; ++q) {
                    const int r = row0 + arow + m * 16 + fq + q;
                    const float mu = acc[m][2 * pr][q] + bmu;
                    const float lv = acc[m][2 * pr + 1][q] + blv;
                    const float e  = eps[(size_t)r * 1024 + d];
                    const float z  = fmaf(expf(0.5f * lv), e, mu);
                    ((unsigned short*)Cv)[(size_t)r * 1088 + d] = f2b(z);
                    klsum += 0.5f * (expf(lv) + mu * mu - 1.f - lv);
                }
            }
        }
        #pragma unroll
        for (int off = 32; off; off >>= 1) klsum += __shfl_xor(klsum, off);
        if (l == 0) wsum[w] = klsum;
        __syncthreads();
        if (t == 0) {
            float s = 0.f;
            #pragma unroll
            for (int i = 0; i < 8; ++i) s += wsum[i];
            atomicAdd(kl, s * (1.0f / 16384.f));
        }
    } else {
        #pragma unroll
        for (int m = 0; m < 8; ++m) {
            #pragma unroll
            for (int n = 0; n < 4; ++n) {
                const int c = col0 + bcol + n * 16 + fr;
                if (EPI == EPI_ZE && c >= 500) continue;
                const int r0 = row0 + arow + m * 16 + fq;
                const float bv = bias[c];
                #pragma unroll
                for (int q = 0; q < 4; ++q) {
                    float v = acc[m][n][q] + bv;
                    if (EPI == EPI_H) v = fmaxf(v, 0.f);
                    if (EPI == EPI_H)
                        ((unsigned short*)Cv)[(size_t)(r0 + q) * ldc + c] = f2b(v);
                    else
                        ((float*)Cv)[(size_t)(r0 + q) * ldc + c] = v;
                }
            }
        }
    }
}

// ---------------------------------------------------------------------------
// logits = x @ cbW^T + lb, split-bf16 (hi*hi + lo*hi + hi*lo), 128^2 tile.
// ---------------------------------------------------------------------------
__global__ __launch_bounds__(256) void gemm_x3_logits(
    const unsigned short* __restrict__ Ah,
    const unsigned short* __restrict__ Al,
    const unsigned short* __restrict__ Bh,
    const unsigned short* __restrict__ Bl,
    const float* __restrict__ bias,
    float* __restrict__ C, int K)
{
    __shared__ short sAh[2 * 4096], sAl[2 * 4096];
    __shared__ short sBh[2 * 4096], sBl[2 * 4096];
    const int t = threadIdx.x, w = t >> 6, l = t & 63;
    const int row0 = blockIdx.y * 128;
    const int wr = (w >> 1) * 64, wc = (w & 1) * 64;
    const size_t aoff = (size_t)(row0 + (t >> 2)) * 768 + ((t & 3) << 3);
    const size_t boff = (size_t)(t >> 2) * 768 + ((t & 3) << 3);
    const size_t step = (size_t)64 * 768;
    const int s0 = t * 8, s1 = (256 + t) * 8;
    const int fr = l & 15, fk = (l >> 4) << 3;
    f32x4 acc[4][4] = {};

    #define STAGE_ALL(buf, k)                                                  \
        stage16(Ah + aoff + (k),        sAh + (buf) * 4096 + s0);              \
        stage16(Ah + aoff + step + (k), sAh + (buf) * 4096 + s1);              \
        stage16(Al + aoff + (k),        sAl + (buf) * 4096 + s0);              \
        stage16(Al + aoff + step + (k), sAl + (buf) * 4096 + s1);              \
        stage16(Bh + boff + (k),        sBh + (buf) * 4096 + s0);              \
        stage16(Bh + boff + step + (k), sBh + (buf) * 4096 + s1);              \
        stage16(Bl + boff + (k),        sBl + (buf) * 4096 + s0);              \
        stage16(Bl + boff + step + (k), sBl + (buf) * 4096 + s1);

    STAGE_ALL(0, 0)
    int cur = 0;
    for (int k0 = 0; k0 < K; k0 += 32) {
        if (k0 + 32 < K) {
            STAGE_ALL(cur ^ 1, k0 + 32)
            asm volatile("s_waitcnt vmcnt(8)" ::: "memory");
        } else {
            asm volatile("s_waitcnt vmcnt(0)" ::: "memory");
        }
        __builtin_amdgcn_s_barrier();
        const short* cAh = sAh + cur * 4096;  const short* cAl = sAl + cur * 4096;
        const short* cBh = sBh + cur * 4096;  const short* cBl = sBl + cur * 4096;
        bf16x8 ah[4], al[4], bh[4], bl[4];
        #pragma unroll
        for (int i = 0; i < 4; ++i) {
            ah[i] = *(const bf16x8*)&cAh[(wr + i * 16 + fr) * 32 + fk];
            al[i] = *(const bf16x8*)&cAl[(wr + i * 16 + fr) * 32 + fk];
        }
        #pragma unroll
        for (int j = 0; j < 4; ++j) {
            bh[j] = *(const bf16x8*)&cBh[(wc + j * 16 + fr) * 32 + fk];
            bl[j] = *(const bf16x8*)&cBl[(wc + j * 16 + fr) * 32 + fk];
        }
        #pragma unroll
        for (int i = 0; i < 4; ++i)
            #pragma unroll
            for (int j = 0; j < 4; ++j) {
                acc[i][j] = __builtin_amdgcn_mfma_f32_16x16x32_bf16(
                    ah[i], bh[j], acc[i][j], 0, 0, 0);
                acc[i][j] = __builtin_amdgcn_mfma_f32_16x16x32_bf16(
                    al[i], bh[j], acc[i][j], 0, 0, 0);
                acc[i][j] = __builtin_amdgcn_mfma_f32_16x16x32_bf16(
                    ah[i], bl[j], acc[i][j], 0, 0, 0);
            }
        __builtin_amdgcn_s_barrier();
        cur ^= 1;
    }
    #undef STAGE_ALL

    const int fq = (l >> 4) << 2;
    #pragma unroll
    for (int i = 0; i < 4; ++i)
        #pragma unroll
        for (int j = 0; j < 4; ++j) {
            const int c = wc + j * 16 + fr;
            if (c < 43) {
                const int r0 = row0 + wr + i * 16 + fq;
                const float bv = bias[c];
                #pragma unroll
                for (int q = 0; q < 4; ++q)
                    C[(size_t)(r0 + q) * 43 + c] = acc[i][j][q] + bv;
            }
        }
}

// ---------------------------------------------------------------------------
// cbW = codebook @ W_enc [43][768] fp64; bf16 hi/lo (rows padded to 128);
// lb = codebook @ b_enc.
// ---------------------------------------------------------------------------
__global__ __launch_bounds__(256) void cbw_kernel(
    const float* __restrict__ W_enc, const float* __restrict__ cb,
    const float* __restrict__ b_enc,
    double* __restrict__ cbWd, unsigned short* __restrict__ cbWh,
    unsigned short* __restrict__ cbWl, float* __restrict__ lbf,
    double* __restrict__ lbd)
{
    const int j = blockIdx.x;   // 0..127
    const int t = threadIdx.x;
    if (j >= 43) {
        for (int d = t; d < 768; d += 256) {
            cbWh[(size_t)j * 768 + d] = 0;
            cbWl[(size_t)j * 768 + d] = 0;
        }
        if (t == 0) lbf[j] = 0.f;
        return;
    }
    double acc[3] = {0.0, 0.0, 0.0};
    for (int k = 0; k < 500; ++k) {
        const double c = (double)cb[(size_t)j * 500 + k];
        acc[0] = fma(c, (double)W_enc[(size_t)k * 768 + t],       acc[0]);
        acc[1] = fma(c, (double)W_enc[(size_t)k * 768 + t + 256], acc[1]);
        acc[2] = fma(c, (double)W_enc[(size_t)k * 768 + t + 512], acc[2]);
    }
    #pragma unroll
    for (int q = 0; q < 3; ++q) {
        const int d = t + q * 256;
        const double v = acc[q];
        cbWd[(size_t)j * 768 + d] = v;
        const float f = (float)v;
        const unsigned short h = f2b(f);
        cbWh[(size_t)j * 768 + d] = h;
        cbWl[(size_t)j * 768 + d] = f2b(f - b2f(h));
    }
    if (t == 0) {
        double s = 0.0;
        for (int k = 0; k < 500; ++k)
            s = fma((double)cb[(size_t)j * 500 + k], (double)b_enc[k], s);
        lbd[j] = s;
        lbf[j] = (float)s;
    }
}

// ---------------------------------------------------------------------------
// Head: argmax (fp64 repair for near-ties), softmax, y (bf16) into Zb cols
// 1024..1087, z_q_x = codebook[argmax].
// ---------------------------------------------------------------------------
__global__ __launch_bounds__(256) void head_kernel(
    const float* __restrict__ logits, const float* __restrict__ codebook,
    const int* __restrict__ known_mask, const int* __restrict__ labels,
    const float* __restrict__ x, const double* __restrict__ cbWd,
    const double* __restrict__ lbd,
    float* __restrict__ zq_out, unsigned short* __restrict__ Zb)
{
    const int wave = threadIdx.x >> 6;
    const int lane = threadIdx.x & 63;
    const int row  = blockIdx.x * 4 + wave;

    const float* lrow = logits + (size_t)row * 43;
    const float v = (lane < 43) ? lrow[lane] : -INFINITY;

    float bvv = v; int bi = lane;
    #pragma unroll
    for (int off = 32; off; off >>= 1) {
        const float ov = __shfl_xor(bvv, off);
        const int   oi = __shfl_xor(bi, off);
        if (ov > bvv || (ov == bvv && oi < bi)) { bvv = ov; bi = oi; }
    }
    float v2 = (lane == bi) ? -INFINITY : v;
    #pragma unroll
    for (int off = 32; off; off >>= 1) v2 = fmaxf(v2, __shfl_xor(v2, off));

    int idx = bi;
    if (bvv - v2 < 1e-3f) {   // near-tie: fp64 recompute (wave-uniform)
        double dv = -1.0e300;
        if (lane < 43) {
            double s = lbd[lane];
            const float* xr = x + (size_t)row * 768;
            const double* wrow = cbWd + (size_t)lane * 768;
            for (int d = 0; d < 768; ++d)
                s = fma((double)xr[d], wrow[d], s);
            dv = s;
        }
        double bdv = dv; int bj = lane;
        #pragma unroll
        for (int off = 32; off; off >>= 1) {
            const double ov = __shfl_xor(bdv, off);
            const int    oi = __shfl_xor(bj, off);
            if (ov > bdv || (ov == bdv && oi < bj)) { bdv = ov; bj = oi; }
        }
        idx = bj;
    }

    float e = (lane < 43) ? expf(v - bvv) : 0.f;
    float s = e;
    #pragma unroll
    for (int off = 32; off; off >>= 1) s += __shfl_xor(s, off);

    const int km  = known_mask[row];
    const int lab = labels[row];
    float y;
    if (lane < 43) y = km ? ((lane == lab) ? 1.f : 0.f) : (e / s);
    else           y = 0.f;   // zeros K-pad cols 1067..1087
    Zb[(size_t)row * 1088 + 1024 + lane] = f2b(y);

    const float* crow = codebook + (size_t)idx * 500;
    float* zrow = zq_out + (size_t)row * 500;
    for (int c = lane; c < 500; c += 64) zrow[c] = crow[c];
}

// f32 -> (hi, lo) bf16 split, n % 4 == 0
__global__ __launch_bounds__(256) void conv_split(
    const float* __restrict__ in,
    unsigned short* __restrict__ hi, unsigned short* __restrict__ lo, int n)
{
    const int i = (blockIdx.x * 256 + threadIdx.x) * 4;
    if (i >= n) return;
    const float4 v = *(const float4*)(in + i);
    ushort4 h, l;
    h.x = f2b(v.x); l.x = f2b(v.x - b2f(h.x));
    h.y = f2b(v.y); l.y = f2b(v.y - b2f(h.y));
    h.z = f2b(v.z); l.z = f2b(v.z - b2f(h.z));
    h.w = f2b(v.w); l.w = f2b(v.w - b2f(h.w));
    *(ushort4*)(hi + i) = h;
    *(ushort4*)(lo + i) = l;
}

// f32 -> bf16 (RNE), n % 4 == 0
__global__ __launch_bounds__(256) void conv_bf16(
    const float* __restrict__ in, unsigned short* __restrict__ out, int n)
{
    const int i = (blockIdx.x * 256 + threadIdx.x) * 4;
    if (i >= n) return;
    const float4 v = *(const float4*)(in + i);
    ushort4 o;
    o.x = f2b(v.x); o.y = f2b(v.y); o.z = f2b(v.z); o.w = f2b(v.w);
    *(ushort4*)(out + i) = o;
}

// W_enc [500][768] -> hi [512][768], rows 500..511 zero
__global__ __launch_bounds__(256) void wenc_hi(
    const float* __restrict__ W, unsigned short* __restrict__ hi)
{
    const int idx = blockIdx.x * 256 + threadIdx.x;
    if (idx >= 512 * 768) return;
    const int r = idx / 768;
    hi[idx] = (r < 500) ? f2b(W[idx]) : 0;
}

// W2 [2048][1024] -> W2p [2048][1024] bf16, rows permuted so that output
// col 32g+s (s<16) = mu_{16g+s} and col 32g+16+s = logvar_{16g+s}.
__global__ __launch_bounds__(256) void repack_w2p(
    const float* __restrict__ W2, unsigned short* __restrict__ W2p)
{
    const int idx = blockIdx.x * 256 + threadIdx.x;
    if (idx >= 2048 * 1024) return;
    const int c = idx >> 10;
    const int k = idx & 1023;
    const int s = c & 31, g = c >> 5;
    const int src = ((s < 16) ? 0 : 1024) + g * 16 + (s & 15);
    W2p[idx] = f2b(W2[(size_t)src * 1024 + k]);
}

// Wd [768][1067] f32 -> [768][1088] bf16, zero K-pad
__global__ __launch_bounds__(256) void repack_wd(
    const float* __restrict__ Wd, unsigned short* __restrict__ Wdb)
{
    const int idx = blockIdx.x * 256 + threadIdx.x;
    if (idx >= 768 * 1088) return;
    const int n = idx / 1088;
    const int k = idx - n * 1088;
    Wdb[idx] = (k < 1067) ? f2b(Wd[(size_t)n * 1067 + k]) : 0;
}

extern "C" void kernel_launch(void* const* d_in, const int* in_sizes, int n_in,
                              void* d_out, int out_size, void* d_ws, size_t ws_size,
                              hipStream_t stream) {
    const float* x        = (const float*)d_in[0];
    const int*   known    = (const int*)  d_in[1];
    const int*   labels   = (const int*)  d_in[2];
    const float* eps      = (const float*)d_in[3];
    const float* W_enc    = (const float*)d_in[4];
    const float* b_enc    = (const float*)d_in[5];
    const float* codebook = (const float*)d_in[6];
    const float* W1       = (const float*)d_in[7];
    const float* b1       = (const float*)d_in[8];
    const float* W2       = (const float*)d_in[9];
    const float* b2       = (const float*)d_in[10];
    const float* Wd       = (const float*)d_in[11];
    const float* bd       = (const float*)d_in[12];
    float* out = (float*)d_out;
    char*  ws  = (char*)d_ws;

    unsigned short* xh   = (unsigned short*)(ws + WS_XH);
    unsigned short* xl   = (unsigned short*)(ws + WS_XL);
    unsigned short* Zb   = (unsigned short*)(ws + WS_ZB);
    unsigned short* hb   = (unsigned short*)(ws + WS_HB);
    unsigned short* W1b  = (unsigned short*)(ws + WS_W1B);
    unsigned short* W2p  = (unsigned short*)(ws + WS_W2P);
    unsigned short* Wdb  = (unsigned short*)(ws + WS_WDB);
    unsigned short* Weh  = (unsigned short*)(ws + WS_WEH);
    unsigned short* cbWh = (unsigned short*)(ws + WS_CBH);
    unsigned short* cbWl = (unsigned short*)(ws + WS_CBL);
    double*         cbWd = (double*)        (ws + WS_CBD);
    float*          lbf  = (float*)         (ws + WS_LBF);
    double*         lbd  = (double*)        (ws + WS_LBD);

    hipMemsetAsync(out + KL_OFF, 0, sizeof(float), stream);

    const dim3 blk(256);
    conv_split<<<(16384 * 768 / 4 + 255) / 256, blk, 0, stream>>>(x, xh, xl, 16384 * 768);
    conv_bf16<<<(1024 * 768 / 4 + 255) / 256, blk, 0, stream>>>(W1, W1b, 1024 * 768);
    repack_w2p<<<(2048 * 1024 + 255) / 256, blk, 0, stream>>>(W2, W2p);
    repack_wd<<<(768 * 1088 + 255) / 256, blk, 0, stream>>>(Wd, Wdb);
    wenc_hi<<<(512 * 768 + 255) / 256, blk, 0, stream>>>(W_enc, Weh);
    cbw_kernel<<<128, blk, 0, stream>>>(W_enc, codebook, b_enc,
                                        cbWd, cbWh, cbWl, lbf, lbd);

    // h = relu(x @ W1^T + b1)   [16384,1024] bf16, grid 4x64=256
    gemm8<EPI_H><<<dim3(256), dim3(512), 0, stream>>>(
        xh, W1b, b1, hb, nullptr, nullptr, 768, 768, 1024, 768, 4);
    // mu_logvar GEMM fused with sampling + KL -> Zb cols 0..1023, grid 8x64=512
    gemm8<EPI_ML><<<dim3(512), dim3(512), 0, stream>>>(
        hb, W2p, b2, Zb, eps, out + KL_OFF, 1024, 1024, 0, 1024, 8);
    // z_e_x = x @ W_enc^T + b_enc   [16384,500] f32, grid 2x64=128
    gemm8<EPI_ZE><<<dim3(128), dim3(512), 0, stream>>>(
        xh, Weh, b_enc, out + ZE_OFF, nullptr, nullptr, 768, 768, 500, 768, 2);
    // logits = x @ cbW^T + lb   [16384,43] f32, split-bf16
    gemm_x3_logits<<<dim3(1, 128), blk, 0, stream>>>(
        xh, xl, cbWh, cbWl, lbf, out + LOG_OFF, 768);
    // head: argmax(+fp64 repair)/softmax/y/z_q_x
    head_kernel<<<B_ROWS / 4, blk, 0, stream>>>(
        out + LOG_OFF, codebook, known, labels, x, cbWd, lbd,
        out + ZQ_OFF, Zb);
    // x_tilde = [sampled_z | y] @ Wd^T + bd   [16384,768] f32, grid 3x64=192
    gemm8<EPI_XT><<<dim3(192), dim3(512), 0, stream>>>(
        Zb, Wdb, bd, out + X_TILDE_OFF, nullptr, nullptr, 1088, 1088, 768, 1088, 3);
}